// Round 10
// baseline (219.790 us; speedup 1.0000x reference)
//
#include <hip/hip_runtime.h>
#include <math.h>

#define D 64
#define GN 128        // nodes per gemm_update (VALU fallback) block
#define BSHIFT 9      // bucket = dst >> 9 (512 nodes per bucket)
#define BN 512        // nodes per bucket
#define MAXB 256      // max buckets (N <= 131072 -> src fits 17 bits)
#define NBLK 256      // partition blocks for hist2d/fill2
#define NBLK_LOG 8
#define SCHUNK 4096   // H entries per scan block (256 thr x 16)

typedef short bf16x8v __attribute__((ext_vector_type(8)));
typedef float f32x4v __attribute__((ext_vector_type(4)));

__device__ __forceinline__ unsigned short f2bf(float f) {   // round-to-nearest-even
    unsigned u = __float_as_uint(f);
    return (unsigned short)((u + 0x7FFFu + ((u >> 16) & 1u)) >> 16);
}
__device__ __forceinline__ float bf2f(unsigned short b) {
    return __uint_as_float(((unsigned)b) << 16);
}

// Detect whether edge_index is int64 (odd int32 words are zero high-halves)
// or int32 (odd words are random node ids).
__global__ void detect_idx64(const int* __restrict__ ei, int* __restrict__ flag) {
    int v = ei[2 * threadIdx.x + 1];
    unsigned long long b = __ballot(v != 0);
    if (threadIdx.x == 0) flag[0] = (b == 0ULL) ? 1 : 0;
}

// Self-test of the assumed 16x16x32 bf16 MFMA fragment layout (exact integer
// arithmetic, transpose-detecting asymmetric inputs). ok=1 iff HW matches.
__global__ void mfma_probe(int* __restrict__ ok) {
    const int l = threadIdx.x;
    const int col = l & 15, grp = l >> 4;
    bf16x8v a, b;
    #pragma unroll
    for (int j = 0; j < 8; ++j) {
        int k = grp * 8 + j;
        a[j] = (short)f2bf((float)(((col * 3 + k) % 7) - 3));      // A[row=col][k]
        b[j] = (short)f2bf((float)(((k * 5 + col * 2) % 9) - 4));  // B[k][n=col]
    }
    f32x4v c = {0.f, 0.f, 0.f, 0.f};
    c = __builtin_amdgcn_mfma_f32_16x16x32_bf16(a, b, c, 0, 0, 0);
    bool good = true;
    #pragma unroll
    for (int r = 0; r < 4; ++r) {
        int row = grp * 4 + r;
        float ref = 0.f;
        for (int k = 0; k < 32; ++k)
            ref += (float)(((row * 3 + k) % 7) - 3) * (float)(((k * 5 + col * 2) % 9) - 4);
        if (c[r] != ref) good = false;
    }
    unsigned long long m = __ballot(good);
    if (l == 0) ok[0] = (m == ~0ULL) ? 1 : 0;
}

// Split the 4 weight matrices (wl0, wr0, wl1, wr1; each 64x64 f32 row-major)
// into bf16 hi/lo arrays with identical layout.
__global__ __launch_bounds__(256) void conv_w4(
        const float* __restrict__ w0, const float* __restrict__ w1,
        const float* __restrict__ w2, const float* __restrict__ w3,
        unsigned short* __restrict__ hi, unsigned short* __restrict__ lo) {
    int i = blockIdx.x * 256 + threadIdx.x;            // 0..16383
    const float* ws_[4] = {w0, w1, w2, w3};
    float f = ws_[i >> 12][i & 4095];
    unsigned short h = f2bf(f);
    hi[i] = h;
    lo[i] = f2bf(f - bf2f(h));
}

// Convert node features f32 -> packed bf16 (uint4 = 8 elems per store).
__global__ __launch_bounds__(256) void conv_xbf(
        const float* __restrict__ x, uint4* __restrict__ xb4, int total8) {
    int i = blockIdx.x * 256 + threadIdx.x;
    int stride = gridDim.x * 256;
    for (; i < total8; i += stride) {
        float4 u0 = *(const float4*)(x + (size_t)i * 8);
        float4 u1 = *(const float4*)(x + (size_t)i * 8 + 4);
        uint4 p;
        p.x = (unsigned)f2bf(u0.x) | ((unsigned)f2bf(u0.y) << 16);
        p.y = (unsigned)f2bf(u0.z) | ((unsigned)f2bf(u0.w) << 16);
        p.z = (unsigned)f2bf(u1.x) | ((unsigned)f2bf(u1.y) << 16);
        p.w = (unsigned)f2bf(u1.z) | ((unsigned)f2bf(u1.w) << 16);
        xb4[i] = p;
    }
}

// ---------------- deterministic counting-sort CSR build ----------------

__global__ __launch_bounds__(256) void hist2d(
        const void* __restrict__ eidx, const int* __restrict__ flagp,
        int* __restrict__ H, int nE, int nb, int epb) {
    __shared__ int h[MAXB];
    const bool idx64 = (*flagp != 0);
    const int* __restrict__ ei32 = (const int*)eidx;
    const long long* __restrict__ ei64 = (const long long*)eidx;
    for (int i = threadIdx.x; i < nb; i += 256) h[i] = 0;
    __syncthreads();
    const int e0 = blockIdx.x * epb;
    const int e1 = min(e0 + epb, nE);
    for (int e = e0 + threadIdx.x; e < e1; e += 256) {
        int d = idx64 ? (int)ei64[e + nE] : ei32[e + nE];
        atomicAdd(&h[d >> BSHIFT], 1);
    }
    __syncthreads();
    for (int i = threadIdx.x; i < nb; i += 256)
        H[(i << NBLK_LOG) + blockIdx.x] = h[i];
}

__global__ __launch_bounds__(256) void scan_h_partial(
        const int* __restrict__ H, int* __restrict__ part, int total) {
    __shared__ int red[4];
    int base = blockIdx.x * SCHUNK + threadIdx.x * 16;
    int s = 0;
    #pragma unroll
    for (int k = 0; k < 16; ++k) { int i = base + k; if (i < total) s += H[i]; }
    #pragma unroll
    for (int off = 32; off >= 1; off >>= 1) s += __shfl_xor(s, off, 64);
    int lane = threadIdx.x & 63, wid = threadIdx.x >> 6;
    if (lane == 0) red[wid] = s;
    __syncthreads();
    if (threadIdx.x == 0) part[blockIdx.x] = red[0] + red[1] + red[2] + red[3];
}

__global__ void scan_h_mid(int* __restrict__ part, int* __restrict__ bbaseN,
                           int nParts, int nE) {
    int tid = threadIdx.x;
    int v = (tid < nParts) ? part[tid] : 0;
    int x = v;
    #pragma unroll
    for (int off = 1; off < 64; off <<= 1) { int y = __shfl_up(x, off, 64); if (tid >= off) x += y; }
    if (tid < nParts) part[tid] = x - v;
    if (tid == 0) bbaseN[0] = nE;
}

__global__ __launch_bounds__(256) void scan_h_final(
        int* __restrict__ H, const int* __restrict__ part,
        int* __restrict__ bbase, int total) {
    __shared__ int wtot[4];
    int tid = threadIdx.x, lane = tid & 63, wid = tid >> 6;
    int base = blockIdx.x * SCHUNK + tid * 16;
    int v[16]; int t = 0;
    #pragma unroll
    for (int k = 0; k < 16; ++k) { int i = base + k; v[k] = (i < total) ? H[i] : 0; t += v[k]; }
    int x = t;
    #pragma unroll
    for (int off = 1; off < 64; off <<= 1) { int y = __shfl_up(x, off, 64); if (lane >= off) x += y; }
    if (lane == 63) wtot[wid] = x;
    __syncthreads();
    int woff = 0;
    for (int w = 0; w < wid; ++w) woff += wtot[w];
    int run = part[blockIdx.x] + woff + (x - t);
    #pragma unroll
    for (int k = 0; k < 16; ++k) {
        int i = base + k;
        if (i < total) {
            H[i] = run;
            if ((i & (NBLK - 1)) == 0) bbase[i >> NBLK_LOG] = run;
            run += v[k];
        }
    }
}

// Packed 4-B pairs: src (bits 0..19) | local-dst (bits 20..28).
__global__ __launch_bounds__(256) void fill2(
        const void* __restrict__ eidx, const int* __restrict__ flagp,
        const int* __restrict__ H, unsigned* __restrict__ pairs,
        int nE, int nb, int epb) {
    __shared__ int cur[MAXB];
    const bool idx64 = (*flagp != 0);
    const int* __restrict__ ei32 = (const int*)eidx;
    const long long* __restrict__ ei64 = (const long long*)eidx;
    for (int i = threadIdx.x; i < nb; i += 256)
        cur[i] = H[(i << NBLK_LOG) + blockIdx.x];
    __syncthreads();
    const int e0 = blockIdx.x * epb;
    const int e1 = min(e0 + epb, nE);
    for (int e = e0 + threadIdx.x; e < e1; e += 256) {
        int s, d;
        if (idx64) { s = (int)ei64[e]; d = (int)ei64[e + nE]; }
        else       { s = ei32[e];      d = ei32[e + nE]; }
        int pos = atomicAdd(&cur[d >> BSHIFT], 1);
        pairs[pos] = (unsigned)s | ((unsigned)(d & (BN - 1)) << 20);
    }
}

__global__ __launch_bounds__(512) void bucket_to_csr(
        const unsigned* __restrict__ pairs,
        const int* __restrict__ bbase,
        int* __restrict__ rowStart, int* __restrict__ srcs,
        int N, int nb, int nE) {
    __shared__ int lcnt[BN];
    __shared__ int lcur[BN];
    __shared__ int wtot[8];
    const int b = blockIdx.x;
    const int base = bbase[b];
    const int cnt  = bbase[b + 1] - base;
    const int tid = threadIdx.x, lane = tid & 63, wid = tid >> 6;
    lcnt[tid] = 0;
    __syncthreads();
    for (int i = tid; i < cnt; i += 512)
        atomicAdd(&lcnt[(int)(pairs[base + i] >> 20)], 1);
    __syncthreads();
    int v = lcnt[tid];
    int x = v;
    #pragma unroll
    for (int off = 1; off < 64; off <<= 1) { int y = __shfl_up(x, off, 64); if (lane >= off) x += y; }
    if (lane == 63) wtot[wid] = x;
    __syncthreads();
    if (tid == 0) {
        int r = 0;
        for (int w = 0; w < 8; ++w) { int t = wtot[w]; wtot[w] = r; r += t; }
    }
    __syncthreads();
    int excl = wtot[wid] + (x - v);
    lcur[tid] = excl;
    int node = b * BN + tid;
    if (node < N) rowStart[node] = base + excl;
    if (b == nb - 1 && tid == 0) rowStart[N] = nE;
    __syncthreads();
    for (int i = tid; i < cnt; i += 512) {
        unsigned p = pairs[base + i];
        int pos = atomicAdd(&lcur[(int)(p >> 20)], 1);
        srcs[base + pos] = (int)(p & 0xFFFFFu);
    }
}

// ---------------- fused layer: gather-mean + split-bf16 MFMA + epilogue ----
// One wave = 16 nodes. Lane (col,grp): node base+col, k-chunks [grp*8, grp*8+8)
// and [32+grp*8, ...) -- exactly the MFMA A-frag layout, so the gathered mean
// feeds MFMA from registers (no agg buffer).
// LAYER 0: neighbors from xb, self from f32 x (hi/lo), ReLU -> bf16 outb.
// LAYER 1: neighbors+self from x1b, L2-normalize -> f32 outf.
#define UNPK8(v, arr)                                                     \
    do {                                                                  \
        arr[0] += __uint_as_float((v).x << 16);                           \
        arr[1] += __uint_as_float((v).x & 0xFFFF0000u);                   \
        arr[2] += __uint_as_float((v).y << 16);                           \
        arr[3] += __uint_as_float((v).y & 0xFFFF0000u);                   \
        arr[4] += __uint_as_float((v).z << 16);                           \
        arr[5] += __uint_as_float((v).z & 0xFFFF0000u);                   \
        arr[6] += __uint_as_float((v).w << 16);                           \
        arr[7] += __uint_as_float((v).w & 0xFFFF0000u);                   \
    } while (0)

template<int LAYER>
__global__ __launch_bounds__(256) void sage_fused(
        const unsigned short* __restrict__ xbNbr,
        const float* __restrict__ xfSelf,
        const int* __restrict__ rowStart,
        const int* __restrict__ srcs,
        const unsigned short* __restrict__ wHi,
        const unsigned short* __restrict__ wLo,
        const float* __restrict__ bl,
        float* __restrict__ outf,
        unsigned short* __restrict__ outb,
        int nNodes, const int* __restrict__ okp) {
    if (!*okp) return;
    const int l = threadIdx.x & 63;
    const int wv = threadIdx.x >> 6;
    const int col = l & 15, grp = l >> 4;
    const int base = blockIdx.x * 64 + wv * 16;
    if (base >= nNodes) return;
    const int anode = min(base + col, nNodes - 1);

    // ---- gather + mean into registers (two 8-wide k-chunks) ----
    const int r0 = rowStart[anode], r1 = rowStart[anode + 1];
    float a0[8] = {0.f,0.f,0.f,0.f,0.f,0.f,0.f,0.f};
    float a1[8] = {0.f,0.f,0.f,0.f,0.f,0.f,0.f,0.f};
    const unsigned short* xp0 = xbNbr + grp * 8;
    const unsigned short* xp1 = xbNbr + 32 + grp * 8;
    int j = r0;
    for (; j + 2 <= r1; j += 2) {
        int s0 = srcs[j], s1 = srcs[j + 1];
        uint4 u0 = *(const uint4*)(xp0 + (size_t)s0 * D);
        uint4 u1 = *(const uint4*)(xp1 + (size_t)s0 * D);
        uint4 u2 = *(const uint4*)(xp0 + (size_t)s1 * D);
        uint4 u3 = *(const uint4*)(xp1 + (size_t)s1 * D);
        UNPK8(u0, a0); UNPK8(u1, a1); UNPK8(u2, a0); UNPK8(u3, a1);
    }
    if (j < r1) {
        int s = srcs[j];
        uint4 u0 = *(const uint4*)(xp0 + (size_t)s * D);
        uint4 u1 = *(const uint4*)(xp1 + (size_t)s * D);
        UNPK8(u0, a0); UNPK8(u1, a1);
    }
    const float invd = 1.0f / fmaxf((float)(r1 - r0), 1.0f);

    // ---- convert mean to hi/lo A-frags (in-register, full precision) ----
    bf16x8v gH[2], gL[2];
    #pragma unroll
    for (int jj = 0; jj < 8; ++jj) {
        float f0 = a0[jj] * invd;
        unsigned short h0 = f2bf(f0);
        gH[0][jj] = (short)h0; gL[0][jj] = (short)f2bf(f0 - bf2f(h0));
        float f1 = a1[jj] * invd;
        unsigned short h1 = f2bf(f1);
        gH[1][jj] = (short)h1; gL[1][jj] = (short)f2bf(f1 - bf2f(h1));
    }

    // ---- self frags ----
    bf16x8v sH[2], sL[2];
    if (LAYER == 0) {
        const float* p = xfSelf + (size_t)anode * D;
        #pragma unroll
        for (int h = 0; h < 2; ++h) {
            const int k0 = h * 32 + grp * 8;
            float4 u0 = *(const float4*)(p + k0);
            float4 u1 = *(const float4*)(p + k0 + 4);
            float v[8] = {u0.x, u0.y, u0.z, u0.w, u1.x, u1.y, u1.z, u1.w};
            #pragma unroll
            for (int jj = 0; jj < 8; ++jj) {
                unsigned short hb = f2bf(v[jj]);
                sH[h][jj] = (short)hb;
                sL[h][jj] = (short)f2bf(v[jj] - bf2f(hb));
            }
        }
    } else {
        #pragma unroll
        for (int h = 0; h < 2; ++h)
            sH[h] = *(const bf16x8v*)(xbNbr + (size_t)anode * D + h * 32 + grp * 8);
    }

    // ---- MFMA: 4 output tiles of 16 features ----
    f32x4v acc[4];
    #pragma unroll
    for (int t = 0; t < 4; ++t) {
        acc[t] = (f32x4v){0.f, 0.f, 0.f, 0.f};
        const unsigned short* whl = wHi + (size_t)(t * 16 + col) * D;
        const unsigned short* wol = wLo + (size_t)(t * 16 + col) * D;
        const unsigned short* whr = whl + 4096;
        const unsigned short* wor = wol + 4096;
        #pragma unroll
        for (int h = 0; h < 2; ++h) {
            const int k0 = h * 32 + grp * 8;
            bf16x8v bh = *(const bf16x8v*)(whl + k0);
            bf16x8v bo = *(const bf16x8v*)(wol + k0);
            acc[t] = __builtin_amdgcn_mfma_f32_16x16x32_bf16(gH[h], bh, acc[t], 0, 0, 0);
            acc[t] = __builtin_amdgcn_mfma_f32_16x16x32_bf16(gL[h], bh, acc[t], 0, 0, 0);
            acc[t] = __builtin_amdgcn_mfma_f32_16x16x32_bf16(gH[h], bo, acc[t], 0, 0, 0);
            bf16x8v bh2 = *(const bf16x8v*)(whr + k0);
            bf16x8v bo2 = *(const bf16x8v*)(wor + k0);
            acc[t] = __builtin_amdgcn_mfma_f32_16x16x32_bf16(sH[h], bh2, acc[t], 0, 0, 0);
            if (LAYER == 0)
                acc[t] = __builtin_amdgcn_mfma_f32_16x16x32_bf16(sL[h], bh2, acc[t], 0, 0, 0);
            acc[t] = __builtin_amdgcn_mfma_f32_16x16x32_bf16(sH[h], bo2, acc[t], 0, 0, 0);
        }
    }

    #pragma unroll
    for (int t = 0; t < 4; ++t) {
        float b = bl[t * 16 + col];
        #pragma unroll
        for (int r = 0; r < 4; ++r) acc[t][r] += b;
    }

    if (LAYER == 0) {
        #pragma unroll
        for (int t = 0; t < 4; ++t)
            #pragma unroll
            for (int r = 0; r < 4; ++r) {
                int n = base + grp * 4 + r;
                if (n < nNodes)
                    outb[(size_t)n * D + t * 16 + col] = f2bf(fmaxf(acc[t][r], 0.f));
            }
    } else {
        float ss[4] = {0.f, 0.f, 0.f, 0.f};
        #pragma unroll
        for (int t = 0; t < 4; ++t)
            #pragma unroll
            for (int r = 0; r < 4; ++r) ss[r] += acc[t][r] * acc[t][r];
        #pragma unroll
        for (int r = 0; r < 4; ++r) {
            #pragma unroll
            for (int off = 1; off < 16; off <<= 1) ss[r] += __shfl_xor(ss[r], off, 64);
        }
        float inv[4];
        #pragma unroll
        for (int r = 0; r < 4; ++r) inv[r] = 1.0f / fmaxf(sqrtf(ss[r]), 1e-12f);
        #pragma unroll
        for (int t = 0; t < 4; ++t)
            #pragma unroll
            for (int r = 0; r < 4; ++r) {
                int n = base + grp * 4 + r;
                if (n < nNodes)
                    outf[(size_t)n * D + t * 16 + col] = acc[t][r] * inv[r];
            }
    }
}

// ---------------- fallback stage 1 (probe failed): gather to agg -----------
__global__ __launch_bounds__(256) void gather_mean_bf16(
        const unsigned short* __restrict__ xb,
        const int* __restrict__ rowStart,
        const int* __restrict__ srcs,
        float* __restrict__ agg,
        int nNodes, const int* __restrict__ okp) {
    if (*okp) return;
    const int tid = threadIdx.x;
    const int gl = tid & 7;
    const int grp = tid >> 3;
    const int node = blockIdx.x * 32 + grp;
    if (node >= nNodes) return;
    const int r0 = rowStart[node], r1 = rowStart[node + 1];
    float a[8] = {0.f,0.f,0.f,0.f,0.f,0.f,0.f,0.f};
    int j = r0;
    for (; j + 2 <= r1; j += 2) {
        int s0 = srcs[j], s1 = srcs[j + 1];
        uint4 v0 = *(const uint4*)(xb + (size_t)s0 * D + gl * 8);
        uint4 v1 = *(const uint4*)(xb + (size_t)s1 * D + gl * 8);
        UNPK8(v0, a); UNPK8(v1, a);
    }
    if (j < r1) {
        uint4 v = *(const uint4*)(xb + (size_t)srcs[j] * D + gl * 8);
        UNPK8(v, a);
    }
    const float inv = 1.0f / fmaxf((float)(r1 - r0), 1.0f);
    float4 o0, o1;
    o0.x = a[0]*inv; o0.y = a[1]*inv; o0.z = a[2]*inv; o0.w = a[3]*inv;
    o1.x = a[4]*inv; o1.y = a[5]*inv; o1.z = a[6]*inv; o1.w = a[7]*inv;
    *(float4*)&agg[(size_t)node * D + gl * 8] = o0;
    *(float4*)&agg[(size_t)node * D + gl * 8 + 4] = o1;
}

// ---------------- fallback stage 2 (probe failed): VALU GEMM ---------------
template<int LAYER>
__global__ __launch_bounds__(256) void gemm_update(
        const float* __restrict__ agg,
        const float* __restrict__ xf,
        const unsigned short* __restrict__ xb,
        const float* __restrict__ wl,
        const float* __restrict__ bl,
        const float* __restrict__ wr,
        float* __restrict__ outf,
        unsigned short* __restrict__ outb,
        int nNodes, const int* __restrict__ okp) {
    if (*okp) return;   // uniform early-exit before any barrier
    __shared__ float sA[D][GN + 4];
    __shared__ float sW[D][D + 4];
    const int tid = threadIdx.x;
    const int fx = tid & 15, nx = tid >> 4;
    const int f0 = fx * 4, n0 = nx * 8;
    const int nb = blockIdx.x * GN;

    float c[8][4];
    #pragma unroll
    for (int i = 0; i < 8; ++i)
        #pragma unroll
        for (int j = 0; j < 4; ++j) c[i][j] = 0.f;

    #pragma unroll
    for (int phase = 0; phase < 2; ++phase) {
        const float* __restrict__ gW = phase ? wr : wl;
        if (phase) __syncthreads();
        for (int i = tid; i < GN * D; i += 256) {
            int n = i >> 6, k = i & 63;
            int gn = nb + n;
            float val = 0.f;
            if (gn < nNodes) {
                if (phase == 0) val = agg[(size_t)gn * D + k];
                else val = LAYER ? bf2f(xb[(size_t)gn * D + k]) : xf[(size_t)gn * D + k];
            }
            sA[k][n] = val;
        }
        for (int i = tid; i < D * D; i += 256) {
            int f = i >> 6, k = i & 63;
            sW[k][f] = gW[i];
        }
        __syncthreads();
        #pragma unroll 8
        for (int k = 0; k < D; ++k) {
            float4 aa0 = *(const float4*)&sA[k][n0];
            float4 aa1 = *(const float4*)&sA[k][n0 + 4];
            float4 w  = *(const float4*)&sW[k][f0];
            float av[8] = {aa0.x, aa0.y, aa0.z, aa0.w, aa1.x, aa1.y, aa1.z, aa1.w};
            float wv[4] = {w.x, w.y, w.z, w.w};
            #pragma unroll
            for (int i = 0; i < 8; ++i)
                #pragma unroll
                for (int j = 0; j < 4; ++j)
                    c[i][j] = fmaf(av[i], wv[j], c[i][j]);
        }
    }

    float4 bv = *(const float4*)&bl[f0];
    float blv[4] = {bv.x, bv.y, bv.z, bv.w};
    #pragma unroll
    for (int i = 0; i < 8; ++i) {
        int gn = nb + n0 + i;
        float o[4];
        #pragma unroll
        for (int j = 0; j < 4; ++j) o[j] = c[i][j] + blv[j];
        if (LAYER == 0) {
            if (gn < nNodes) {
                #pragma unroll
                for (int j = 0; j < 4; ++j)
                    outb[(size_t)gn * D + f0 + j] = f2bf(fmaxf(o[j], 0.f));
            }
        } else {
            float ss = o[0]*o[0] + o[1]*o[1] + o[2]*o[2] + o[3]*o[3];
            #pragma unroll
            for (int off = 8; off >= 1; off >>= 1) ss += __shfl_xor(ss, off, 16);
            float inv = 1.0f / fmaxf(sqrtf(ss), 1e-12f);
            #pragma unroll
            for (int j = 0; j < 4; ++j) o[j] *= inv;
            if (gn < nNodes) {
                float4 ov; ov.x = o[0]; ov.y = o[1]; ov.z = o[2]; ov.w = o[3];
                *(float4*)&outf[(size_t)gn * D + f0] = ov;
            }
        }
    }
}

// ---------------- fallback: atomic scatter path (ws too small) -------------

__global__ __launch_bounds__(256) void sage_scatter(
        const float* __restrict__ x,
        const void* __restrict__ eidx,
        const int* __restrict__ flagp,
        float* __restrict__ agg,
        float* __restrict__ deg,
        int nE, int doDeg) {
    const bool idx64 = (*flagp != 0);
    const int lane = threadIdx.x & 63;
    int wave = (int)((blockIdx.x * blockDim.x + threadIdx.x) >> 6);
    const int waveStride = (int)((gridDim.x * blockDim.x) >> 6);
    const int* __restrict__ ei32 = (const int*)eidx;
    const long long* __restrict__ ei64 = (const long long*)eidx;
    for (int e = wave; e < nE; e += waveStride) {
        int s, d;
        if (idx64) { s = (int)ei64[e]; d = (int)ei64[e + nE]; }
        else       { s = ei32[e];      d = ei32[e + nE]; }
        atomicAdd(&agg[(size_t)d * D + lane], x[(size_t)s * D + lane]);
        if (doDeg && lane == 0) atomicAdd(&deg[d], 1.0f);
    }
}

__global__ __launch_bounds__(256) void sage_update(
        const float* __restrict__ xin,
        const float* __restrict__ agg,
        const float* __restrict__ deg,
        const float* __restrict__ wl,
        const float* __restrict__ bl,
        const float* __restrict__ wr,
        float* __restrict__ xout,
        int nNodes, int mode) {
    __shared__ float wlT[D * D];
    __shared__ float wrT[D * D];
    __shared__ float rowA[4][D];
    __shared__ float rowX[4][D];
    for (int i = threadIdx.x; i < D * D; i += blockDim.x) {
        int f = i >> 6, k = i & 63;
        wlT[k * D + f] = wl[i];
        wrT[k * D + f] = wr[i];
    }
    __syncthreads();
    const int lane = threadIdx.x & 63;
    const int wid = threadIdx.x >> 6;
    const float blv = bl[lane];
    for (int node = blockIdx.x * 4 + wid; node < nNodes; node += gridDim.x * 4) {
        float dg = fmaxf(deg[node], 1.0f);
        float a  = agg[(size_t)node * D + lane] / dg;
        float xv = xin[(size_t)node * D + lane];
        rowA[wid][lane] = a;
        rowX[wid][lane] = xv;
        float acc = blv;
        #pragma unroll
        for (int k = 0; k < D; ++k) {
            acc = fmaf(rowA[wid][k], wlT[k * D + lane], acc);
            acc = fmaf(rowX[wid][k], wrT[k * D + lane], acc);
        }
        if (mode == 0) {
            xout[(size_t)node * D + lane] = fmaxf(acc, 0.0f);
        } else {
            float ss = acc * acc;
            #pragma unroll
            for (int off = 32; off >= 1; off >>= 1) ss += __shfl_xor(ss, off, 64);
            xout[(size_t)node * D + lane] = acc / fmaxf(sqrtf(ss), 1e-12f);
        }
    }
}

extern "C" void kernel_launch(void* const* d_in, const int* in_sizes, int n_in,
                              void* d_out, int out_size, void* d_ws, size_t ws_size,
                              hipStream_t stream) {
    const float* x   = (const float*)d_in[0];
    const float* wl0 = (const float*)d_in[1];
    const float* bl0 = (const float*)d_in[2];
    const float* wr0 = (const float*)d_in[3];
    const float* wl1 = (const float*)d_in[4];
    const float* bl1 = (const float*)d_in[5];
    const float* wr1 = (const float*)d_in[6];
    const void*  ei  = d_in[7];
    float* out = (float*)d_out;

    const int N = in_sizes[0] / D;
    const int E = in_sizes[7] / 2;
    const int NB = (N + BN - 1) / BN;
    const int EPB = (E + NBLK - 1) / NBLK;
    const int TOTAL = NB << NBLK_LOG;
    const int NPARTS = (TOTAL + SCHUNK - 1) / SCHUNK;

    char* ws = (char*)d_ws;
    size_t off = 0;
    auto alloc = [&](size_t bytes) { void* p = ws + off; off = (off + bytes + 255) & ~(size_t)255; return p; };

    // regionA: pairs (E*4) then xb (N*D*2) -- strict serial lifetimes.
    size_t regionA_bytes = (size_t)E * 4;
    if ((size_t)N * D * 2 > regionA_bytes) regionA_bytes = (size_t)N * D * 2;
    size_t need = 0;
    {
        size_t o = 0;
        auto sim = [&](size_t b) { o = (o + b + 255) & ~(size_t)255; };
        sim(4); sim(4); sim(16384 * 2); sim(16384 * 2);
        sim(((size_t)MAXB << NBLK_LOG) * 4); sim(64 * 4); sim(((size_t)MAXB + 1) * 4);
        sim(((size_t)N + 1) * 4); sim((size_t)E * 4);
        sim(regionA_bytes); sim((size_t)N * D * 2); sim((size_t)N * D * 4);
        need = o;
    }

    if (ws_size >= need && NB <= MAXB && NPARTS <= 64) {
        int* flag     = (int*)alloc(4);
        int* okf      = (int*)alloc(4);
        unsigned short* whi = (unsigned short*)alloc(16384 * 2);
        unsigned short* wlo = (unsigned short*)alloc(16384 * 2);
        int* H        = (int*)alloc(((size_t)MAXB << NBLK_LOG) * 4);
        int* part     = (int*)alloc(64 * 4);
        int* bbase    = (int*)alloc(((size_t)MAXB + 1) * 4);
        int* rowStart = (int*)alloc(((size_t)N + 1) * 4);
        int* srcs     = (int*)alloc((size_t)E * 4);
        void* regionA = alloc(regionA_bytes);
        unsigned short* x1b = (unsigned short*)alloc((size_t)N * D * 2);
        float* agg    = (float*)alloc((size_t)N * D * 4);   // fallback path only
        unsigned* pairs = (unsigned*)regionA;
        unsigned short* xb = (unsigned short*)regionA;      // after bucket_to_csr

        detect_idx64<<<1, 64, 0, stream>>>((const int*)ei, flag);
        mfma_probe<<<1, 64, 0, stream>>>(okf);
        conv_w4<<<64, 256, 0, stream>>>(wl0, wr0, wl1, wr1, whi, wlo);
        hist2d<<<NBLK, 256, 0, stream>>>(ei, flag, H, E, NB, EPB);
        scan_h_partial<<<NPARTS, 256, 0, stream>>>(H, part, TOTAL);
        scan_h_mid<<<1, 64, 0, stream>>>(part, &bbase[NB], NPARTS, E);
        scan_h_final<<<NPARTS, 256, 0, stream>>>(H, part, bbase, TOTAL);
        fill2<<<NBLK, 256, 0, stream>>>(ei, flag, H, pairs, E, NB, EPB);
        bucket_to_csr<<<NB, 512, 0, stream>>>(pairs, bbase, rowStart, srcs, N, NB, E);
        conv_xbf<<<1024, 256, 0, stream>>>(x, (uint4*)xb, N * 8);   // regionA reuse

        const int gFused  = (N + 63) / 64;
        const int gGather = (N + 31) / 32;
        const int gGemm   = (N + GN - 1) / GN;
        // MFMA path (runs iff probe ok)
        sage_fused<0><<<gFused, 256, 0, stream>>>(xb, x, rowStart, srcs,
                                                  whi, wlo, bl0, (float*)0, x1b, N, okf);
        sage_fused<1><<<gFused, 256, 0, stream>>>(x1b, (const float*)0, rowStart, srcs,
                                                  whi + 2 * 4096, wlo + 2 * 4096, bl1,
                                                  out, (unsigned short*)0, N, okf);
        // VALU fallback path (runs iff probe failed)
        gather_mean_bf16<<<gGather, 256, 0, stream>>>(xb, rowStart, srcs, agg, N, okf);
        gemm_update<0><<<gGemm, 256, 0, stream>>>(agg, x, (const unsigned short*)0,
                                                  wl0, bl0, wr0, (float*)0, x1b, N, okf);
        gather_mean_bf16<<<gGather, 256, 0, stream>>>(x1b, rowStart, srcs, agg, N, okf);
        gemm_update<1><<<gGemm, 256, 0, stream>>>(agg, (const float*)0, x1b,
                                                  wl1, bl1, wr1, out, (unsigned short*)0, N, okf);
    } else {
        // fallback: round-1 scatter path (~26 MB ws)
        int*   flag = (int*)alloc(4);
        float* deg  = (float*)alloc((size_t)N * 4);
        float* agg  = (float*)alloc((size_t)N * D * 4);
        float* x1   = out;  // safe: sage_update reads only its own row of xin

        detect_idx64<<<1, 64, 0, stream>>>((const int*)ei, flag);
        hipMemsetAsync(deg, 0, ((size_t)N + (size_t)N * D) * 4, stream);
        sage_scatter<<<4096, 256, 0, stream>>>(x, ei, flag, agg, deg, E, 1);
        sage_update<<<2048, 256, 0, stream>>>(x, agg, deg, wl0, bl0, wr0, x1, N, 0);
        hipMemsetAsync(agg, 0, (size_t)N * D * 4, stream);
        sage_scatter<<<4096, 256, 0, stream>>>(x1, ei, flag, agg, deg, E, 0);
        sage_update<<<2048, 256, 0, stream>>>(x1, agg, deg, wl1, bl1, wr1, out, N, 1);
    }
}

// Round 11
// 193.640 us; speedup vs baseline: 1.1350x; 1.1350x over previous
//
#include <hip/hip_runtime.h>
#include <math.h>

#define D 64
#define GN 128        // nodes per gemm_update (VALU fallback) block
#define BSHIFT 9      // bucket = dst >> 9 (512 nodes per bucket)
#define BN 512        // nodes per bucket
#define MAXB 256      // max buckets (N <= 131072 -> src fits 20 bits)
#define NBLK 256      // partition blocks for hist2d/fill2
#define NBLK_LOG 8
#define SCHUNK 4096   // H entries per scan block (256 thr x 16)

typedef short bf16x8v __attribute__((ext_vector_type(8)));
typedef float f32x4v __attribute__((ext_vector_type(4)));

__device__ __forceinline__ unsigned short f2bf(float f) {   // round-to-nearest-even
    unsigned u = __float_as_uint(f);
    return (unsigned short)((u + 0x7FFFu + ((u >> 16) & 1u)) >> 16);
}
__device__ __forceinline__ float bf2f(unsigned short b) {
    return __uint_as_float(((unsigned)b) << 16);
}

// Detect whether edge_index is int64 (odd int32 words are zero high-halves)
// or int32 (odd words are random node ids).
__global__ void detect_idx64(const int* __restrict__ ei, int* __restrict__ flag) {
    int v = ei[2 * threadIdx.x + 1];
    unsigned long long b = __ballot(v != 0);
    if (threadIdx.x == 0) flag[0] = (b == 0ULL) ? 1 : 0;
}

// Self-test of the assumed 16x16x32 bf16 MFMA fragment layout (exact integer
// arithmetic, transpose-detecting asymmetric inputs). ok=1 iff HW matches.
__global__ void mfma_probe(int* __restrict__ ok) {
    const int l = threadIdx.x;
    const int col = l & 15, grp = l >> 4;
    bf16x8v a, b;
    #pragma unroll
    for (int j = 0; j < 8; ++j) {
        int k = grp * 8 + j;
        a[j] = (short)f2bf((float)(((col * 3 + k) % 7) - 3));      // A[row=col][k]
        b[j] = (short)f2bf((float)(((k * 5 + col * 2) % 9) - 4));  // B[k][n=col]
    }
    f32x4v c = {0.f, 0.f, 0.f, 0.f};
    c = __builtin_amdgcn_mfma_f32_16x16x32_bf16(a, b, c, 0, 0, 0);
    bool good = true;
    #pragma unroll
    for (int r = 0; r < 4; ++r) {
        int row = grp * 4 + r;
        float ref = 0.f;
        for (int k = 0; k < 32; ++k)
            ref += (float)(((row * 3 + k) % 7) - 3) * (float)(((k * 5 + col * 2) % 9) - 4);
        if (c[r] != ref) good = false;
    }
    unsigned long long m = __ballot(good);
    if (l == 0) ok[0] = (m == ~0ULL) ? 1 : 0;
}

// Split the 4 weight matrices (wl0, wr0, wl1, wr1; each 64x64 f32 row-major)
// into bf16 hi/lo arrays with identical layout.
__global__ __launch_bounds__(256) void conv_w4(
        const float* __restrict__ w0, const float* __restrict__ w1,
        const float* __restrict__ w2, const float* __restrict__ w3,
        unsigned short* __restrict__ hi, unsigned short* __restrict__ lo) {
    int i = blockIdx.x * 256 + threadIdx.x;            // 0..16383
    const float* ws_[4] = {w0, w1, w2, w3};
    float f = ws_[i >> 12][i & 4095];
    unsigned short h = f2bf(f);
    hi[i] = h;
    lo[i] = f2bf(f - bf2f(h));
}

// Convert node features f32 -> packed bf16 (uint4 = 8 elems per store).
__global__ __launch_bounds__(256) void conv_xbf(
        const float* __restrict__ x, uint4* __restrict__ xb4, int total8) {
    int i = blockIdx.x * 256 + threadIdx.x;
    int stride = gridDim.x * 256;
    for (; i < total8; i += stride) {
        float4 u0 = *(const float4*)(x + (size_t)i * 8);
        float4 u1 = *(const float4*)(x + (size_t)i * 8 + 4);
        uint4 p;
        p.x = (unsigned)f2bf(u0.x) | ((unsigned)f2bf(u0.y) << 16);
        p.y = (unsigned)f2bf(u0.z) | ((unsigned)f2bf(u0.w) << 16);
        p.z = (unsigned)f2bf(u1.x) | ((unsigned)f2bf(u1.y) << 16);
        p.w = (unsigned)f2bf(u1.z) | ((unsigned)f2bf(u1.w) << 16);
        xb4[i] = p;
    }
}

// ---------------- deterministic counting-sort CSR build ----------------

__global__ __launch_bounds__(256) void hist2d(
        const void* __restrict__ eidx, const int* __restrict__ flagp,
        int* __restrict__ H, int nE, int nb, int epb) {
    __shared__ int h[MAXB];
    const bool idx64 = (*flagp != 0);
    const int* __restrict__ ei32 = (const int*)eidx;
    const long long* __restrict__ ei64 = (const long long*)eidx;
    for (int i = threadIdx.x; i < nb; i += 256) h[i] = 0;
    __syncthreads();
    const int e0 = blockIdx.x * epb;
    const int e1 = min(e0 + epb, nE);
    for (int e = e0 + threadIdx.x; e < e1; e += 256) {
        int d = idx64 ? (int)ei64[e + nE] : ei32[e + nE];
        atomicAdd(&h[d >> BSHIFT], 1);
    }
    __syncthreads();
    for (int i = threadIdx.x; i < nb; i += 256)
        H[(i << NBLK_LOG) + blockIdx.x] = h[i];
}

__global__ __launch_bounds__(256) void scan_h_partial(
        const int* __restrict__ H, int* __restrict__ part, int total) {
    __shared__ int red[4];
    int base = blockIdx.x * SCHUNK + threadIdx.x * 16;
    int s = 0;
    #pragma unroll
    for (int k = 0; k < 16; ++k) { int i = base + k; if (i < total) s += H[i]; }
    #pragma unroll
    for (int off = 32; off >= 1; off >>= 1) s += __shfl_xor(s, off, 64);
    int lane = threadIdx.x & 63, wid = threadIdx.x >> 6;
    if (lane == 0) red[wid] = s;
    __syncthreads();
    if (threadIdx.x == 0) part[blockIdx.x] = red[0] + red[1] + red[2] + red[3];
}

__global__ void scan_h_mid(int* __restrict__ part, int* __restrict__ bbaseN,
                           int nParts, int nE) {
    int tid = threadIdx.x;
    int v = (tid < nParts) ? part[tid] : 0;
    int x = v;
    #pragma unroll
    for (int off = 1; off < 64; off <<= 1) { int y = __shfl_up(x, off, 64); if (tid >= off) x += y; }
    if (tid < nParts) part[tid] = x - v;
    if (tid == 0) bbaseN[0] = nE;
}

__global__ __launch_bounds__(256) void scan_h_final(
        int* __restrict__ H, const int* __restrict__ part,
        int* __restrict__ bbase, int total) {
    __shared__ int wtot[4];
    int tid = threadIdx.x, lane = tid & 63, wid = tid >> 6;
    int base = blockIdx.x * SCHUNK + tid * 16;
    int v[16]; int t = 0;
    #pragma unroll
    for (int k = 0; k < 16; ++k) { int i = base + k; v[k] = (i < total) ? H[i] : 0; t += v[k]; }
    int x = t;
    #pragma unroll
    for (int off = 1; off < 64; off <<= 1) { int y = __shfl_up(x, off, 64); if (lane >= off) x += y; }
    if (lane == 63) wtot[wid] = x;
    __syncthreads();
    int woff = 0;
    for (int w = 0; w < wid; ++w) woff += wtot[w];
    int run = part[blockIdx.x] + woff + (x - t);
    #pragma unroll
    for (int k = 0; k < 16; ++k) {
        int i = base + k;
        if (i < total) {
            H[i] = run;
            if ((i & (NBLK - 1)) == 0) bbase[i >> NBLK_LOG] = run;
            run += v[k];
        }
    }
}

// Packed 4-B pairs: src (bits 0..19) | local-dst (bits 20..28).
__global__ __launch_bounds__(256) void fill2(
        const void* __restrict__ eidx, const int* __restrict__ flagp,
        const int* __restrict__ H, unsigned* __restrict__ pairs,
        int nE, int nb, int epb) {
    __shared__ int cur[MAXB];
    const bool idx64 = (*flagp != 0);
    const int* __restrict__ ei32 = (const int*)eidx;
    const long long* __restrict__ ei64 = (const long long*)eidx;
    for (int i = threadIdx.x; i < nb; i += 256)
        cur[i] = H[(i << NBLK_LOG) + blockIdx.x];
    __syncthreads();
    const int e0 = blockIdx.x * epb;
    const int e1 = min(e0 + epb, nE);
    for (int e = e0 + threadIdx.x; e < e1; e += 256) {
        int s, d;
        if (idx64) { s = (int)ei64[e]; d = (int)ei64[e + nE]; }
        else       { s = ei32[e];      d = ei32[e + nE]; }
        int pos = atomicAdd(&cur[d >> BSHIFT], 1);
        pairs[pos] = (unsigned)s | ((unsigned)(d & (BN - 1)) << 20);
    }
}

__global__ __launch_bounds__(512) void bucket_to_csr(
        const unsigned* __restrict__ pairs,
        const int* __restrict__ bbase,
        int* __restrict__ rowStart, int* __restrict__ srcs,
        int N, int nb, int nE) {
    __shared__ int lcnt[BN];
    __shared__ int lcur[BN];
    __shared__ int wtot[8];
    const int b = blockIdx.x;
    const int base = bbase[b];
    const int cnt  = bbase[b + 1] - base;
    const int tid = threadIdx.x, lane = tid & 63, wid = tid >> 6;
    lcnt[tid] = 0;
    __syncthreads();
    for (int i = tid; i < cnt; i += 512)
        atomicAdd(&lcnt[(int)(pairs[base + i] >> 20)], 1);
    __syncthreads();
    int v = lcnt[tid];
    int x = v;
    #pragma unroll
    for (int off = 1; off < 64; off <<= 1) { int y = __shfl_up(x, off, 64); if (lane >= off) x += y; }
    if (lane == 63) wtot[wid] = x;
    __syncthreads();
    if (tid == 0) {
        int r = 0;
        for (int w = 0; w < 8; ++w) { int t = wtot[w]; wtot[w] = r; r += t; }
    }
    __syncthreads();
    int excl = wtot[wid] + (x - v);
    lcur[tid] = excl;
    int node = b * BN + tid;
    if (node < N) rowStart[node] = base + excl;
    if (b == nb - 1 && tid == 0) rowStart[N] = nE;
    __syncthreads();
    for (int i = tid; i < cnt; i += 512) {
        unsigned p = pairs[base + i];
        int pos = atomicAdd(&lcur[(int)(p >> 20)], 1);
        srcs[base + pos] = (int)(p & 0xFFFFFu);
    }
}

// ---------------- layer stage 1: gather + mean from bf16 features ----------
// 8 lanes per node (lane = 8-feature chunk, 16-B uint4 load), 32 nodes/block,
// unroll 4 -> 4 row loads in flight per lane. Tiny VGPR -> max occupancy (TLP).
#define UNPK8(v, arr)                                                     \
    do {                                                                  \
        arr[0] += __uint_as_float((v).x << 16);                           \
        arr[1] += __uint_as_float((v).x & 0xFFFF0000u);                   \
        arr[2] += __uint_as_float((v).y << 16);                           \
        arr[3] += __uint_as_float((v).y & 0xFFFF0000u);                   \
        arr[4] += __uint_as_float((v).z << 16);                           \
        arr[5] += __uint_as_float((v).z & 0xFFFF0000u);                   \
        arr[6] += __uint_as_float((v).w << 16);                           \
        arr[7] += __uint_as_float((v).w & 0xFFFF0000u);                   \
    } while (0)

__global__ __launch_bounds__(256) void gather_mean_bf16(
        const unsigned short* __restrict__ xb,
        const int* __restrict__ rowStart,
        const int* __restrict__ srcs,
        float* __restrict__ agg,
        int nNodes) {
    const int tid = threadIdx.x;
    const int gl = tid & 7;
    const int grp = tid >> 3;
    const int node = blockIdx.x * 32 + grp;
    if (node >= nNodes) return;
    const int r0 = rowStart[node], r1 = rowStart[node + 1];
    float a[8] = {0.f,0.f,0.f,0.f,0.f,0.f,0.f,0.f};
    const unsigned short* xp = xb + gl * 8;
    int j = r0;
    for (; j + 4 <= r1; j += 4) {
        int s0 = srcs[j], s1 = srcs[j + 1], s2 = srcs[j + 2], s3 = srcs[j + 3];
        uint4 v0 = *(const uint4*)(xp + (size_t)s0 * D);
        uint4 v1 = *(const uint4*)(xp + (size_t)s1 * D);
        uint4 v2 = *(const uint4*)(xp + (size_t)s2 * D);
        uint4 v3 = *(const uint4*)(xp + (size_t)s3 * D);
        UNPK8(v0, a); UNPK8(v1, a); UNPK8(v2, a); UNPK8(v3, a);
    }
    if (j + 2 <= r1) {
        int s0 = srcs[j], s1 = srcs[j + 1];
        uint4 v0 = *(const uint4*)(xp + (size_t)s0 * D);
        uint4 v1 = *(const uint4*)(xp + (size_t)s1 * D);
        UNPK8(v0, a); UNPK8(v1, a);
        j += 2;
    }
    if (j < r1) {
        uint4 v = *(const uint4*)(xp + (size_t)srcs[j] * D);
        UNPK8(v, a);
    }
    const float inv = 1.0f / fmaxf((float)(r1 - r0), 1.0f);
    float4 o0, o1;
    o0.x = a[0]*inv; o0.y = a[1]*inv; o0.z = a[2]*inv; o0.w = a[3]*inv;
    o1.x = a[4]*inv; o1.y = a[5]*inv; o1.z = a[6]*inv; o1.w = a[7]*inv;
    *(float4*)&agg[(size_t)node * D + gl * 8] = o0;
    *(float4*)&agg[(size_t)node * D + gl * 8 + 4] = o1;
}

// ---------------- layer stage 2: split-bf16 MFMA GEMM, 2 tiles/wave --------
// Each wave: 32 nodes (2 tiles of 16). A-loads for both tiles issued first;
// weight frags shared across tiles (same address -> loaded once).
// LAYER 0: self from f32 x (hi/lo), ReLU -> bf16 outb.
// LAYER 1: self from bf16 x1b (hi only), L2-normalize -> f32 outf.
template<int LAYER>
__global__ __launch_bounds__(256) void gemm_mfma(
        const float* __restrict__ agg,
        const float* __restrict__ xf,
        const unsigned short* __restrict__ xb,
        const unsigned short* __restrict__ wHi,
        const unsigned short* __restrict__ wLo,
        const float* __restrict__ bl,
        float* __restrict__ outf,
        unsigned short* __restrict__ outb,
        int nNodes, const int* __restrict__ okp) {
    if (!*okp) return;
    const int l = threadIdx.x & 63;
    const int wv = threadIdx.x >> 6;
    const int col = l & 15, grp = l >> 4;
    const int base0 = blockIdx.x * 128 + wv * 32;
    if (base0 >= nNodes) return;

    // ---- A frags for both tiles (all global loads issued up front) ----
    bf16x8v gH[2][2], gL[2][2], sH[2][2], sL[2][2];   // [tile][h]
    #pragma unroll
    for (int tt = 0; tt < 2; ++tt) {
        const int anode = min(base0 + tt * 16 + col, nNodes - 1);
        const float* p = agg + (size_t)anode * D;
        #pragma unroll
        for (int h = 0; h < 2; ++h) {
            const int k0 = h * 32 + grp * 8;
            float4 u0 = *(const float4*)(p + k0);
            float4 u1 = *(const float4*)(p + k0 + 4);
            float v[8] = {u0.x, u0.y, u0.z, u0.w, u1.x, u1.y, u1.z, u1.w};
            #pragma unroll
            for (int jj = 0; jj < 8; ++jj) {
                unsigned short hb = f2bf(v[jj]);
                gH[tt][h][jj] = (short)hb;
                gL[tt][h][jj] = (short)f2bf(v[jj] - bf2f(hb));
            }
        }
        if (LAYER == 0) {
            const float* ps = xf + (size_t)anode * D;
            #pragma unroll
            for (int h = 0; h < 2; ++h) {
                const int k0 = h * 32 + grp * 8;
                float4 u0 = *(const float4*)(ps + k0);
                float4 u1 = *(const float4*)(ps + k0 + 4);
                float v[8] = {u0.x, u0.y, u0.z, u0.w, u1.x, u1.y, u1.z, u1.w};
                #pragma unroll
                for (int jj = 0; jj < 8; ++jj) {
                    unsigned short hb = f2bf(v[jj]);
                    sH[tt][h][jj] = (short)hb;
                    sL[tt][h][jj] = (short)f2bf(v[jj] - bf2f(hb));
                }
            }
        } else {
            #pragma unroll
            for (int h = 0; h < 2; ++h)
                sH[tt][h] = *(const bf16x8v*)(xb + (size_t)anode * D + h * 32 + grp * 8);
        }
    }

    // ---- MFMA: weight frags loaded once per (t,h), used by both tiles ----
    f32x4v acc[2][4];
    #pragma unroll
    for (int tt = 0; tt < 2; ++tt)
        #pragma unroll
        for (int t = 0; t < 4; ++t) acc[tt][t] = (f32x4v){0.f, 0.f, 0.f, 0.f};

    #pragma unroll
    for (int t = 0; t < 4; ++t) {
        const unsigned short* whl = wHi + (size_t)(t * 16 + col) * D;
        const unsigned short* wol = wLo + (size_t)(t * 16 + col) * D;
        const unsigned short* whr = whl + 4096;
        const unsigned short* wor = wol + 4096;
        #pragma unroll
        for (int h = 0; h < 2; ++h) {
            const int k0 = h * 32 + grp * 8;
            bf16x8v bh  = *(const bf16x8v*)(whl + k0);
            bf16x8v bo  = *(const bf16x8v*)(wol + k0);
            bf16x8v bh2 = *(const bf16x8v*)(whr + k0);
            bf16x8v bo2 = *(const bf16x8v*)(wor + k0);
            #pragma unroll
            for (int tt = 0; tt < 2; ++tt) {
                acc[tt][t] = __builtin_amdgcn_mfma_f32_16x16x32_bf16(gH[tt][h], bh,  acc[tt][t], 0, 0, 0);
                acc[tt][t] = __builtin_amdgcn_mfma_f32_16x16x32_bf16(gL[tt][h], bh,  acc[tt][t], 0, 0, 0);
                acc[tt][t] = __builtin_amdgcn_mfma_f32_16x16x32_bf16(gH[tt][h], bo,  acc[tt][t], 0, 0, 0);
                acc[tt][t] = __builtin_amdgcn_mfma_f32_16x16x32_bf16(sH[tt][h], bh2, acc[tt][t], 0, 0, 0);
                if (LAYER == 0)
                    acc[tt][t] = __builtin_amdgcn_mfma_f32_16x16x32_bf16(sL[tt][h], bh2, acc[tt][t], 0, 0, 0);
                acc[tt][t] = __builtin_amdgcn_mfma_f32_16x16x32_bf16(sH[tt][h], bo2, acc[tt][t], 0, 0, 0);
            }
        }
    }

    // ---- epilogue per tile ----
    #pragma unroll
    for (int tt = 0; tt < 2; ++tt) {
        const int base = base0 + tt * 16;
        #pragma unroll
        for (int t = 0; t < 4; ++t) {
            float b = bl[t * 16 + col];
            #pragma unroll
            for (int r = 0; r < 4; ++r) acc[tt][t][r] += b;
        }
        if (LAYER == 0) {
            #pragma unroll
            for (int t = 0; t < 4; ++t)
                #pragma unroll
                for (int r = 0; r < 4; ++r) {
                    int n = base + grp * 4 + r;
                    if (n < nNodes)
                        outb[(size_t)n * D + t * 16 + col] = f2bf(fmaxf(acc[tt][t][r], 0.f));
                }
        } else {
            float ss[4] = {0.f, 0.f, 0.f, 0.f};
            #pragma unroll
            for (int t = 0; t < 4; ++t)
                #pragma unroll
                for (int r = 0; r < 4; ++r) ss[r] += acc[tt][t][r] * acc[tt][t][r];
            #pragma unroll
            for (int r = 0; r < 4; ++r) {
                #pragma unroll
                for (int off = 1; off < 16; off <<= 1) ss[r] += __shfl_xor(ss[r], off, 64);
            }
            float inv[4];
            #pragma unroll
            for (int r = 0; r < 4; ++r) inv[r] = 1.0f / fmaxf(sqrtf(ss[r]), 1e-12f);
            #pragma unroll
            for (int t = 0; t < 4; ++t)
                #pragma unroll
                for (int r = 0; r < 4; ++r) {
                    int n = base + grp * 4 + r;
                    if (n < nNodes)
                        outf[(size_t)n * D + t * 16 + col] = acc[tt][t][r] * inv[r];
                }
        }
    }
}

// ---------------- fallback stage 2 (probe failed): VALU GEMM ---------------
template<int LAYER>
__global__ __launch_bounds__(256) void gemm_update(
        const float* __restrict__ agg,
        const float* __restrict__ xf,
        const unsigned short* __restrict__ xb,
        const float* __restrict__ wl,
        const float* __restrict__ bl,
        const float* __restrict__ wr,
        float* __restrict__ outf,
        unsigned short* __restrict__ outb,
        int nNodes, const int* __restrict__ okp) {
    if (*okp) return;   // uniform early-exit before any barrier
    __shared__ float sA[D][GN + 4];
    __shared__ float sW[D][D + 4];
    const int tid = threadIdx.x;
    const int fx = tid & 15, nx = tid >> 4;
    const int f0 = fx * 4, n0 = nx * 8;
    const int nb = blockIdx.x * GN;

    float c[8][4];
    #pragma unroll
    for (int i = 0; i < 8; ++i)
        #pragma unroll
        for (int j = 0; j < 4; ++j) c[i][j] = 0.f;

    #pragma unroll
    for (int phase = 0; phase < 2; ++phase) {
        const float* __restrict__ gW = phase ? wr : wl;
        if (phase) __syncthreads();
        for (int i = tid; i < GN * D; i += 256) {
            int n = i >> 6, k = i & 63;
            int gn = nb + n;
            float val = 0.f;
            if (gn < nNodes) {
                if (phase == 0) val = agg[(size_t)gn * D + k];
                else val = LAYER ? bf2f(xb[(size_t)gn * D + k]) : xf[(size_t)gn * D + k];
            }
            sA[k][n] = val;
        }
        for (int i = tid; i < D * D; i += 256) {
            int f = i >> 6, k = i & 63;
            sW[k][f] = gW[i];
        }
        __syncthreads();
        #pragma unroll 8
        for (int k = 0; k < D; ++k) {
            float4 aa0 = *(const float4*)&sA[k][n0];
            float4 aa1 = *(const float4*)&sA[k][n0 + 4];
            float4 w  = *(const float4*)&sW[k][f0];
            float av[8] = {aa0.x, aa0.y, aa0.z, aa0.w, aa1.x, aa1.y, aa1.z, aa1.w};
            float wv[4] = {w.x, w.y, w.z, w.w};
            #pragma unroll
            for (int i = 0; i < 8; ++i)
                #pragma unroll
                for (int j = 0; j < 4; ++j)
                    c[i][j] = fmaf(av[i], wv[j], c[i][j]);
        }
    }

    float4 bv = *(const float4*)&bl[f0];
    float blv[4] = {bv.x, bv.y, bv.z, bv.w};
    #pragma unroll
    for (int i = 0; i < 8; ++i) {
        int gn = nb + n0 + i;
        float o[4];
        #pragma unroll
        for (int j = 0; j < 4; ++j) o[j] = c[i][j] + blv[j];
        if (LAYER == 0) {
            if (gn < nNodes) {
                #pragma unroll
                for (int j = 0; j < 4; ++j)
                    outb[(size_t)gn * D + f0 + j] = f2bf(fmaxf(o[j], 0.f));
            }
        } else {
            float ss = o[0]*o[0] + o[1]*o[1] + o[2]*o[2] + o[3]*o[3];
            #pragma unroll
            for (int off = 8; off >= 1; off >>= 1) ss += __shfl_xor(ss, off, 16);
            float inv = 1.0f / fmaxf(sqrtf(ss), 1e-12f);
            #pragma unroll
            for (int j = 0; j < 4; ++j) o[j] *= inv;
            if (gn < nNodes) {
                float4 ov; ov.x = o[0]; ov.y = o[1]; ov.z = o[2]; ov.w = o[3];
                *(float4*)&outf[(size_t)gn * D + f0] = ov;
            }
        }
    }
}

// ---------------- fallback: atomic scatter path (ws too small) -------------

__global__ __launch_bounds__(256) void sage_scatter(
        const float* __restrict__ x,
        const void* __restrict__ eidx,
        const int* __restrict__ flagp,
        float* __restrict__ agg,
        float* __restrict__ deg,
        int nE, int doDeg) {
    const bool idx64 = (*flagp != 0);
    const int lane = threadIdx.x & 63;
    int wave = (int)((blockIdx.x * blockDim.x + threadIdx.x) >> 6);
    const int waveStride = (int)((gridDim.x * blockDim.x) >> 6);
    const int* __restrict__ ei32 = (const int*)eidx;
    const long long* __restrict__ ei64 = (const long long*)eidx;
    for (int e = wave; e < nE; e += waveStride) {
        int s, d;
        if (idx64) { s = (int)ei64[e]; d = (int)ei64[e + nE]; }
        else       { s = ei32[e];      d = ei32[e + nE]; }
        atomicAdd(&agg[(size_t)d * D + lane], x[(size_t)s * D + lane]);
        if (doDeg && lane == 0) atomicAdd(&deg[d], 1.0f);
    }
}

__global__ __launch_bounds__(256) void sage_update(
        const float* __restrict__ xin,
        const float* __restrict__ agg,
        const float* __restrict__ deg,
        const float* __restrict__ wl,
        const float* __restrict__ bl,
        const float* __restrict__ wr,
        float* __restrict__ xout,
        int nNodes, int mode) {
    __shared__ float wlT[D * D];
    __shared__ float wrT[D * D];
    __shared__ float rowA[4][D];
    __shared__ float rowX[4][D];
    for (int i = threadIdx.x; i < D * D; i += blockDim.x) {
        int f = i >> 6, k = i & 63;
        wlT[k * D + f] = wl[i];
        wrT[k * D + f] = wr[i];
    }
    __syncthreads();
    const int lane = threadIdx.x & 63;
    const int wid = threadIdx.x >> 6;
    const float blv = bl[lane];
    for (int node = blockIdx.x * 4 + wid; node < nNodes; node += gridDim.x * 4) {
        float dg = fmaxf(deg[node], 1.0f);
        float a  = agg[(size_t)node * D + lane] / dg;
        float xv = xin[(size_t)node * D + lane];
        rowA[wid][lane] = a;
        rowX[wid][lane] = xv;
        float acc = blv;
        #pragma unroll
        for (int k = 0; k < D; ++k) {
            acc = fmaf(rowA[wid][k], wlT[k * D + lane], acc);
            acc = fmaf(rowX[wid][k], wrT[k * D + lane], acc);
        }
        if (mode == 0) {
            xout[(size_t)node * D + lane] = fmaxf(acc, 0.0f);
        } else {
            float ss = acc * acc;
            #pragma unroll
            for (int off = 32; off >= 1; off >>= 1) ss += __shfl_xor(ss, off, 64);
            xout[(size_t)node * D + lane] = acc / fmaxf(sqrtf(ss), 1e-12f);
        }
    }
}

extern "C" void kernel_launch(void* const* d_in, const int* in_sizes, int n_in,
                              void* d_out, int out_size, void* d_ws, size_t ws_size,
                              hipStream_t stream) {
    const float* x   = (const float*)d_in[0];
    const float* wl0 = (const float*)d_in[1];
    const float* bl0 = (const float*)d_in[2];
    const float* wr0 = (const float*)d_in[3];
    const float* wl1 = (const float*)d_in[4];
    const float* bl1 = (const float*)d_in[5];
    const float* wr1 = (const float*)d_in[6];
    const void*  ei  = d_in[7];
    float* out = (float*)d_out;

    const int N = in_sizes[0] / D;
    const int E = in_sizes[7] / 2;
    const int NB = (N + BN - 1) / BN;
    const int EPB = (E + NBLK - 1) / NBLK;
    const int TOTAL = NB << NBLK_LOG;
    const int NPARTS = (TOTAL + SCHUNK - 1) / SCHUNK;

    char* ws = (char*)d_ws;
    size_t off = 0;
    auto alloc = [&](size_t bytes) { void* p = ws + off; off = (off + bytes + 255) & ~(size_t)255; return p; };

    // regionA: pairs (E*4) then xb (N*D*2) -- strict serial lifetimes.
    size_t regionA_bytes = (size_t)E * 4;
    if ((size_t)N * D * 2 > regionA_bytes) regionA_bytes = (size_t)N * D * 2;
    size_t need = 0;
    {
        size_t o = 0;
        auto sim = [&](size_t b) { o = (o + b + 255) & ~(size_t)255; };
        sim(4); sim(4); sim(16384 * 2); sim(16384 * 2);
        sim(((size_t)MAXB << NBLK_LOG) * 4); sim(64 * 4); sim(((size_t)MAXB + 1) * 4);
        sim(((size_t)N + 1) * 4); sim((size_t)E * 4);
        sim(regionA_bytes); sim((size_t)N * D * 2); sim((size_t)N * D * 4);
        need = o;
    }

    if (ws_size >= need && NB <= MAXB && NPARTS <= 64) {
        int* flag     = (int*)alloc(4);
        int* okf      = (int*)alloc(4);
        unsigned short* whi = (unsigned short*)alloc(16384 * 2);
        unsigned short* wlo = (unsigned short*)alloc(16384 * 2);
        int* H        = (int*)alloc(((size_t)MAXB << NBLK_LOG) * 4);
        int* part     = (int*)alloc(64 * 4);
        int* bbase    = (int*)alloc(((size_t)MAXB + 1) * 4);
        int* rowStart = (int*)alloc(((size_t)N + 1) * 4);
        int* srcs     = (int*)alloc((size_t)E * 4);
        void* regionA = alloc(regionA_bytes);
        unsigned short* x1b = (unsigned short*)alloc((size_t)N * D * 2);
        float* agg    = (float*)alloc((size_t)N * D * 4);
        unsigned* pairs = (unsigned*)regionA;
        unsigned short* xb = (unsigned short*)regionA;      // after bucket_to_csr

        detect_idx64<<<1, 64, 0, stream>>>((const int*)ei, flag);
        mfma_probe<<<1, 64, 0, stream>>>(okf);
        conv_w4<<<64, 256, 0, stream>>>(wl0, wr0, wl1, wr1, whi, wlo);
        hist2d<<<NBLK, 256, 0, stream>>>(ei, flag, H, E, NB, EPB);
        scan_h_partial<<<NPARTS, 256, 0, stream>>>(H, part, TOTAL);
        scan_h_mid<<<1, 64, 0, stream>>>(part, &bbase[NB], NPARTS, E);
        scan_h_final<<<NPARTS, 256, 0, stream>>>(H, part, bbase, TOTAL);
        fill2<<<NBLK, 256, 0, stream>>>(ei, flag, H, pairs, E, NB, EPB);
        bucket_to_csr<<<NB, 512, 0, stream>>>(pairs, bbase, rowStart, srcs, N, NB, E);
        conv_xbf<<<1024, 256, 0, stream>>>(x, (uint4*)xb, N * 8);   // regionA reuse

        const int gGather = (N + 31) / 32;
        const int gMfma   = (N + 127) / 128;
        const int gGemm   = (N + GN - 1) / GN;
        // layer 0
        gather_mean_bf16<<<gGather, 256, 0, stream>>>(xb, rowStart, srcs, agg, N);
        gemm_mfma<0><<<gMfma, 256, 0, stream>>>(agg, x, (const unsigned short*)0,
                                                whi, wlo, bl0, (float*)0, x1b, N, okf);
        gemm_update<0><<<gGemm, 256, 0, stream>>>(agg, x, (const unsigned short*)0,
                                                  wl0, bl0, wr0, (float*)0, x1b, N, okf);
        // layer 1
        gather_mean_bf16<<<gGather, 256, 0, stream>>>(x1b, rowStart, srcs, agg, N);
        gemm_mfma<1><<<gMfma, 256, 0, stream>>>(agg, (const float*)0, x1b,
                                                whi + 2 * 4096, wlo + 2 * 4096, bl1,
                                                out, (unsigned short*)0, N, okf);
        gemm_update<1><<<gGemm, 256, 0, stream>>>(agg, (const float*)0, x1b,
                                                  wl1, bl1, wr1, out, (unsigned short*)0, N, okf);
    } else {
        // fallback: round-1 scatter path (~26 MB ws)
        int*   flag = (int*)alloc(4);
        float* deg  = (float*)alloc((size_t)N * 4);
        float* agg  = (float*)alloc((size_t)N * D * 4);
        float* x1   = out;  // safe: sage_update reads only its own row of xin

        detect_idx64<<<1, 64, 0, stream>>>((const int*)ei, flag);
        hipMemsetAsync(deg, 0, ((size_t)N + (size_t)N * D) * 4, stream);
        sage_scatter<<<4096, 256, 0, stream>>>(x, ei, flag, agg, deg, E, 1);
        sage_update<<<2048, 256, 0, stream>>>(x, agg, deg, wl0, bl0, wr0, x1, N, 0);
        hipMemsetAsync(agg, 0, (size_t)N * D * 4, stream);
        sage_scatter<<<4096, 256, 0, stream>>>(x1, ei, flag, agg, deg, E, 0);
        sage_update<<<2048, 256, 0, stream>>>(x1, agg, deg, wl1, bl1, wr1, out, N, 1);
    }
}

// Round 12
// 178.682 us; speedup vs baseline: 1.2301x; 1.0837x over previous
//
#include <hip/hip_runtime.h>
#include <math.h>

#define D 64
#define BSHIFT 9      // bucket = dst >> 9 (512 nodes per bucket)
#define BN 512        // nodes per bucket
#define MAXB 256      // max buckets (N <= 131072 -> src fits 20 bits)
#define NBLK 256      // partition blocks for hist2d/fill2
#define NBLK_LOG 8
#define SCHUNK 4096   // H entries per scan block (256 thr x 16)

typedef short bf16x8v __attribute__((ext_vector_type(8)));
typedef float f32x4v __attribute__((ext_vector_type(4)));

__device__ __forceinline__ unsigned short f2bf(float f) {   // round-to-nearest-even
    unsigned u = __float_as_uint(f);
    return (unsigned short)((u + 0x7FFFu + ((u >> 16) & 1u)) >> 16);
}
__device__ __forceinline__ float bf2f(unsigned short b) {
    return __uint_as_float(((unsigned)b) << 16);
}

// Detect whether edge_index is int64 (odd int32 words are zero high-halves)
// or int32 (odd words are random node ids).
__global__ void detect_idx64(const int* __restrict__ ei, int* __restrict__ flag) {
    int v = ei[2 * threadIdx.x + 1];
    unsigned long long b = __ballot(v != 0);
    if (threadIdx.x == 0) flag[0] = (b == 0ULL) ? 1 : 0;
}

// Split the 4 weight matrices (wl0, wr0, wl1, wr1; each 64x64 f32 row-major)
// into bf16 hi/lo arrays with identical layout.
__global__ __launch_bounds__(256) void conv_w4(
        const float* __restrict__ w0, const float* __restrict__ w1,
        const float* __restrict__ w2, const float* __restrict__ w3,
        unsigned short* __restrict__ hi, unsigned short* __restrict__ lo) {
    int i = blockIdx.x * 256 + threadIdx.x;            // 0..16383
    const float* ws_[4] = {w0, w1, w2, w3};
    float f = ws_[i >> 12][i & 4095];
    unsigned short h = f2bf(f);
    hi[i] = h;
    lo[i] = f2bf(f - bf2f(h));
}

// Convert node features f32 -> packed bf16 (uint4 = 8 elems per store).
__global__ __launch_bounds__(256) void conv_xbf(
        const float* __restrict__ x, uint4* __restrict__ xb4, int total8) {
    int i = blockIdx.x * 256 + threadIdx.x;
    int stride = gridDim.x * 256;
    for (; i < total8; i += stride) {
        float4 u0 = *(const float4*)(x + (size_t)i * 8);
        float4 u1 = *(const float4*)(x + (size_t)i * 8 + 4);
        uint4 p;
        p.x = (unsigned)f2bf(u0.x) | ((unsigned)f2bf(u0.y) << 16);
        p.y = (unsigned)f2bf(u0.z) | ((unsigned)f2bf(u0.w) << 16);
        p.z = (unsigned)f2bf(u1.x) | ((unsigned)f2bf(u1.y) << 16);
        p.w = (unsigned)f2bf(u1.z) | ((unsigned)f2bf(u1.w) << 16);
        xb4[i] = p;
    }
}

// ---------------- deterministic counting-sort CSR build ----------------

__global__ __launch_bounds__(256) void hist2d(
        const void* __restrict__ eidx, const int* __restrict__ flagp,
        int* __restrict__ H, int nE, int nb, int epb) {
    __shared__ int h[MAXB];
    const bool idx64 = (*flagp != 0);
    const int* __restrict__ ei32 = (const int*)eidx;
    const long long* __restrict__ ei64 = (const long long*)eidx;
    for (int i = threadIdx.x; i < nb; i += 256) h[i] = 0;
    __syncthreads();
    const int e0 = blockIdx.x * epb;
    const int e1 = min(e0 + epb, nE);
    for (int e = e0 + threadIdx.x; e < e1; e += 256) {
        int d = idx64 ? (int)ei64[e + nE] : ei32[e + nE];
        atomicAdd(&h[d >> BSHIFT], 1);
    }
    __syncthreads();
    for (int i = threadIdx.x; i < nb; i += 256)
        H[(i << NBLK_LOG) + blockIdx.x] = h[i];
}

__global__ __launch_bounds__(256) void scan_h_partial(
        const int* __restrict__ H, int* __restrict__ part, int total) {
    __shared__ int red[4];
    int base = blockIdx.x * SCHUNK + threadIdx.x * 16;
    int s = 0;
    #pragma unroll
    for (int k = 0; k < 16; ++k) { int i = base + k; if (i < total) s += H[i]; }
    #pragma unroll
    for (int off = 32; off >= 1; off >>= 1) s += __shfl_xor(s, off, 64);
    int lane = threadIdx.x & 63, wid = threadIdx.x >> 6;
    if (lane == 0) red[wid] = s;
    __syncthreads();
    if (threadIdx.x == 0) part[blockIdx.x] = red[0] + red[1] + red[2] + red[3];
}

__global__ void scan_h_mid(int* __restrict__ part, int* __restrict__ bbaseN,
                           int nParts, int nE) {
    int tid = threadIdx.x;
    int v = (tid < nParts) ? part[tid] : 0;
    int x = v;
    #pragma unroll
    for (int off = 1; off < 64; off <<= 1) { int y = __shfl_up(x, off, 64); if (tid >= off) x += y; }
    if (tid < nParts) part[tid] = x - v;
    if (tid == 0) bbaseN[0] = nE;
}

__global__ __launch_bounds__(256) void scan_h_final(
        int* __restrict__ H, const int* __restrict__ part,
        int* __restrict__ bbase, int total) {
    __shared__ int wtot[4];
    int tid = threadIdx.x, lane = tid & 63, wid = tid >> 6;
    int base = blockIdx.x * SCHUNK + tid * 16;
    int v[16]; int t = 0;
    #pragma unroll
    for (int k = 0; k < 16; ++k) { int i = base + k; v[k] = (i < total) ? H[i] : 0; t += v[k]; }
    int x = t;
    #pragma unroll
    for (int off = 1; off < 64; off <<= 1) { int y = __shfl_up(x, off, 64); if (lane >= off) x += y; }
    if (lane == 63) wtot[wid] = x;
    __syncthreads();
    int woff = 0;
    for (int w = 0; w < wid; ++w) woff += wtot[w];
    int run = part[blockIdx.x] + woff + (x - t);
    #pragma unroll
    for (int k = 0; k < 16; ++k) {
        int i = base + k;
        if (i < total) {
            H[i] = run;
            if ((i & (NBLK - 1)) == 0) bbase[i >> NBLK_LOG] = run;
            run += v[k];
        }
    }
}

// Packed 4-B pairs: src (bits 0..19) | local-dst (bits 20..28).
__global__ __launch_bounds__(256) void fill2(
        const void* __restrict__ eidx, const int* __restrict__ flagp,
        const int* __restrict__ H, unsigned* __restrict__ pairs,
        int nE, int nb, int epb) {
    __shared__ int cur[MAXB];
    const bool idx64 = (*flagp != 0);
    const int* __restrict__ ei32 = (const int*)eidx;
    const long long* __restrict__ ei64 = (const long long*)eidx;
    for (int i = threadIdx.x; i < nb; i += 256)
        cur[i] = H[(i << NBLK_LOG) + blockIdx.x];
    __syncthreads();
    const int e0 = blockIdx.x * epb;
    const int e1 = min(e0 + epb, nE);
    for (int e = e0 + threadIdx.x; e < e1; e += 256) {
        int s, d;
        if (idx64) { s = (int)ei64[e]; d = (int)ei64[e + nE]; }
        else       { s = ei32[e];      d = ei32[e + nE]; }
        int pos = atomicAdd(&cur[d >> BSHIFT], 1);
        pairs[pos] = (unsigned)s | ((unsigned)(d & (BN - 1)) << 20);
    }
}

__global__ __launch_bounds__(512) void bucket_to_csr(
        const unsigned* __restrict__ pairs,
        const int* __restrict__ bbase,
        int* __restrict__ rowStart, int* __restrict__ srcs,
        int N, int nb, int nE) {
    __shared__ int lcnt[BN];
    __shared__ int lcur[BN];
    __shared__ int wtot[8];
    const int b = blockIdx.x;
    const int base = bbase[b];
    const int cnt  = bbase[b + 1] - base;
    const int tid = threadIdx.x, lane = tid & 63, wid = tid >> 6;
    lcnt[tid] = 0;
    __syncthreads();
    for (int i = tid; i < cnt; i += 512)
        atomicAdd(&lcnt[(int)(pairs[base + i] >> 20)], 1);
    __syncthreads();
    int v = lcnt[tid];
    int x = v;
    #pragma unroll
    for (int off = 1; off < 64; off <<= 1) { int y = __shfl_up(x, off, 64); if (lane >= off) x += y; }
    if (lane == 63) wtot[wid] = x;
    __syncthreads();
    if (tid == 0) {
        int r = 0;
        for (int w = 0; w < 8; ++w) { int t = wtot[w]; wtot[w] = r; r += t; }
    }
    __syncthreads();
    int excl = wtot[wid] + (x - v);
    lcur[tid] = excl;
    int node = b * BN + tid;
    if (node < N) rowStart[node] = base + excl;
    if (b == nb - 1 && tid == 0) rowStart[N] = nE;
    __syncthreads();
    for (int i = tid; i < cnt; i += 512) {
        unsigned p = pairs[base + i];
        int pos = atomicAdd(&lcur[(int)(p >> 20)], 1);
        srcs[base + pos] = (int)(p & 0xFFFFFu);
    }
}

// ---------------- layer stage 1: gather + mean (bf16 in, bf16 out) ---------
// 8 lanes per node (lane = 8-feature chunk, 16-B uint4 load), 32 nodes/block,
// unroll 4 -> 4 row loads in flight per lane. f32 accumulate, bf16 store.
#define UNPK8(v, arr)                                                     \
    do {                                                                  \
        arr[0] += __uint_as_float((v).x << 16);                           \
        arr[1] += __uint_as_float((v).x & 0xFFFF0000u);                   \
        arr[2] += __uint_as_float((v).y << 16);                           \
        arr[3] += __uint_as_float((v).y & 0xFFFF0000u);                   \
        arr[4] += __uint_as_float((v).z << 16);                           \
        arr[5] += __uint_as_float((v).z & 0xFFFF0000u);                   \
        arr[6] += __uint_as_float((v).w << 16);                           \
        arr[7] += __uint_as_float((v).w & 0xFFFF0000u);                   \
    } while (0)

__global__ __launch_bounds__(256) void gather_mean_bf16(
        const unsigned short* __restrict__ xb,
        const int* __restrict__ rowStart,
        const int* __restrict__ srcs,
        unsigned short* __restrict__ aggb,
        int nNodes) {
    const int tid = threadIdx.x;
    const int gl = tid & 7;
    const int grp = tid >> 3;
    const int node = blockIdx.x * 32 + grp;
    if (node >= nNodes) return;
    const int r0 = rowStart[node], r1 = rowStart[node + 1];
    float a[8] = {0.f,0.f,0.f,0.f,0.f,0.f,0.f,0.f};
    const unsigned short* xp = xb + gl * 8;
    int j = r0;
    for (; j + 4 <= r1; j += 4) {
        int s0 = srcs[j], s1 = srcs[j + 1], s2 = srcs[j + 2], s3 = srcs[j + 3];
        uint4 v0 = *(const uint4*)(xp + (size_t)s0 * D);
        uint4 v1 = *(const uint4*)(xp + (size_t)s1 * D);
        uint4 v2 = *(const uint4*)(xp + (size_t)s2 * D);
        uint4 v3 = *(const uint4*)(xp + (size_t)s3 * D);
        UNPK8(v0, a); UNPK8(v1, a); UNPK8(v2, a); UNPK8(v3, a);
    }
    if (j + 2 <= r1) {
        int s0 = srcs[j], s1 = srcs[j + 1];
        uint4 v0 = *(const uint4*)(xp + (size_t)s0 * D);
        uint4 v1 = *(const uint4*)(xp + (size_t)s1 * D);
        UNPK8(v0, a); UNPK8(v1, a);
        j += 2;
    }
    if (j < r1) {
        uint4 v = *(const uint4*)(xp + (size_t)srcs[j] * D);
        UNPK8(v, a);
    }
    const float inv = 1.0f / fmaxf((float)(r1 - r0), 1.0f);
    uint4 p;
    p.x = (unsigned)f2bf(a[0]*inv) | ((unsigned)f2bf(a[1]*inv) << 16);
    p.y = (unsigned)f2bf(a[2]*inv) | ((unsigned)f2bf(a[3]*inv) << 16);
    p.z = (unsigned)f2bf(a[4]*inv) | ((unsigned)f2bf(a[5]*inv) << 16);
    p.w = (unsigned)f2bf(a[6]*inv) | ((unsigned)f2bf(a[7]*inv) << 16);
    *(uint4*)(aggb + (size_t)node * D + gl * 8) = p;
}

// ---------------- layer stage 2: split-bf16 MFMA GEMM, 2 tiles/wave --------
// Each wave: 32 nodes (2 tiles of 16). A-loads for both tiles issued first;
// weight frags shared across tiles (same address -> loaded once).
// Neighbor term from bf16 aggb (hi only; weights still hi+lo).
// LAYER 0: self from f32 x (hi/lo), ReLU -> bf16 outb.
// LAYER 1: self from bf16 x1b (hi only), L2-normalize -> f32 outf.
template<int LAYER>
__global__ __launch_bounds__(256) void gemm_mfma(
        const unsigned short* __restrict__ aggb,
        const float* __restrict__ xf,
        const unsigned short* __restrict__ xb,
        const unsigned short* __restrict__ wHi,
        const unsigned short* __restrict__ wLo,
        const float* __restrict__ bl,
        float* __restrict__ outf,
        unsigned short* __restrict__ outb,
        int nNodes) {
    const int l = threadIdx.x & 63;
    const int wv = threadIdx.x >> 6;
    const int col = l & 15, grp = l >> 4;
    const int base0 = blockIdx.x * 128 + wv * 32;
    if (base0 >= nNodes) return;

    // ---- A frags for both tiles (all global loads issued up front) ----
    bf16x8v gH[2][2], sH[2][2], sL[2][2];   // [tile][h]
    #pragma unroll
    for (int tt = 0; tt < 2; ++tt) {
        const int anode = min(base0 + tt * 16 + col, nNodes - 1);
        #pragma unroll
        for (int h = 0; h < 2; ++h)
            gH[tt][h] = *(const bf16x8v*)(aggb + (size_t)anode * D + h * 32 + grp * 8);
        if (LAYER == 0) {
            const float* ps = xf + (size_t)anode * D;
            #pragma unroll
            for (int h = 0; h < 2; ++h) {
                const int k0 = h * 32 + grp * 8;
                float4 u0 = *(const float4*)(ps + k0);
                float4 u1 = *(const float4*)(ps + k0 + 4);
                float v[8] = {u0.x, u0.y, u0.z, u0.w, u1.x, u1.y, u1.z, u1.w};
                #pragma unroll
                for (int jj = 0; jj < 8; ++jj) {
                    unsigned short hb = f2bf(v[jj]);
                    sH[tt][h][jj] = (short)hb;
                    sL[tt][h][jj] = (short)f2bf(v[jj] - bf2f(hb));
                }
            }
        } else {
            #pragma unroll
            for (int h = 0; h < 2; ++h)
                sH[tt][h] = *(const bf16x8v*)(xb + (size_t)anode * D + h * 32 + grp * 8);
        }
    }

    // ---- MFMA: weight frags loaded once per (t,h), used by both tiles ----
    f32x4v acc[2][4];
    #pragma unroll
    for (int tt = 0; tt < 2; ++tt)
        #pragma unroll
        for (int t = 0; t < 4; ++t) acc[tt][t] = (f32x4v){0.f, 0.f, 0.f, 0.f};

    #pragma unroll
    for (int t = 0; t < 4; ++t) {
        const unsigned short* whl = wHi + (size_t)(t * 16 + col) * D;
        const unsigned short* wol = wLo + (size_t)(t * 16 + col) * D;
        const unsigned short* whr = whl + 4096;
        const unsigned short* wor = wol + 4096;
        #pragma unroll
        for (int h = 0; h < 2; ++h) {
            const int k0 = h * 32 + grp * 8;
            bf16x8v bh  = *(const bf16x8v*)(whl + k0);
            bf16x8v bo  = *(const bf16x8v*)(wol + k0);
            bf16x8v bh2 = *(const bf16x8v*)(whr + k0);
            bf16x8v bo2 = *(const bf16x8v*)(wor + k0);
            #pragma unroll
            for (int tt = 0; tt < 2; ++tt) {
                acc[tt][t] = __builtin_amdgcn_mfma_f32_16x16x32_bf16(gH[tt][h], bh,  acc[tt][t], 0, 0, 0);
                acc[tt][t] = __builtin_amdgcn_mfma_f32_16x16x32_bf16(gH[tt][h], bo,  acc[tt][t], 0, 0, 0);
                acc[tt][t] = __builtin_amdgcn_mfma_f32_16x16x32_bf16(sH[tt][h], bh2, acc[tt][t], 0, 0, 0);
                if (LAYER == 0)
                    acc[tt][t] = __builtin_amdgcn_mfma_f32_16x16x32_bf16(sL[tt][h], bh2, acc[tt][t], 0, 0, 0);
                acc[tt][t] = __builtin_amdgcn_mfma_f32_16x16x32_bf16(sH[tt][h], bo2, acc[tt][t], 0, 0, 0);
            }
        }
    }

    // ---- epilogue per tile ----
    #pragma unroll
    for (int tt = 0; tt < 2; ++tt) {
        const int base = base0 + tt * 16;
        #pragma unroll
        for (int t = 0; t < 4; ++t) {
            float b = bl[t * 16 + col];
            #pragma unroll
            for (int r = 0; r < 4; ++r) acc[tt][t][r] += b;
        }
        if (LAYER == 0) {
            #pragma unroll
            for (int t = 0; t < 4; ++t)
                #pragma unroll
                for (int r = 0; r < 4; ++r) {
                    int n = base + grp * 4 + r;
                    if (n < nNodes)
                        outb[(size_t)n * D + t * 16 + col] = f2bf(fmaxf(acc[tt][t][r], 0.f));
                }
        } else {
            float ss[4] = {0.f, 0.f, 0.f, 0.f};
            #pragma unroll
            for (int t = 0; t < 4; ++t)
                #pragma unroll
                for (int r = 0; r < 4; ++r) ss[r] += acc[tt][t][r] * acc[tt][t][r];
            #pragma unroll
            for (int r = 0; r < 4; ++r) {
                #pragma unroll
                for (int off = 1; off < 16; off <<= 1) ss[r] += __shfl_xor(ss[r], off, 64);
            }
            float inv[4];
            #pragma unroll
            for (int r = 0; r < 4; ++r) inv[r] = 1.0f / fmaxf(sqrtf(ss[r]), 1e-12f);
            #pragma unroll
            for (int t = 0; t < 4; ++t)
                #pragma unroll
                for (int r = 0; r < 4; ++r) {
                    int n = base + grp * 4 + r;
                    if (n < nNodes)
                        outf[(size_t)n * D + t * 16 + col] = acc[tt][t][r] * inv[r];
                }
        }
    }
}

// ---------------- fallback: atomic scatter path (ws too small) -------------

__global__ __launch_bounds__(256) void sage_scatter(
        const float* __restrict__ x,
        const void* __restrict__ eidx,
        const int* __restrict__ flagp,
        float* __restrict__ agg,
        float* __restrict__ deg,
        int nE, int doDeg) {
    const bool idx64 = (*flagp != 0);
    const int lane = threadIdx.x & 63;
    int wave = (int)((blockIdx.x * blockDim.x + threadIdx.x) >> 6);
    const int waveStride = (int)((gridDim.x * blockDim.x) >> 6);
    const int* __restrict__ ei32 = (const int*)eidx;
    const long long* __restrict__ ei64 = (const long long*)eidx;
    for (int e = wave; e < nE; e += waveStride) {
        int s, d;
        if (idx64) { s = (int)ei64[e]; d = (int)ei64[e + nE]; }
        else       { s = ei32[e];      d = ei32[e + nE]; }
        atomicAdd(&agg[(size_t)d * D + lane], x[(size_t)s * D + lane]);
        if (doDeg && lane == 0) atomicAdd(&deg[d], 1.0f);
    }
}

__global__ __launch_bounds__(256) void sage_update(
        const float* __restrict__ xin,
        const float* __restrict__ agg,
        const float* __restrict__ deg,
        const float* __restrict__ wl,
        const float* __restrict__ bl,
        const float* __restrict__ wr,
        float* __restrict__ xout,
        int nNodes, int mode) {
    __shared__ float wlT[D * D];
    __shared__ float wrT[D * D];
    __shared__ float rowA[4][D];
    __shared__ float rowX[4][D];
    for (int i = threadIdx.x; i < D * D; i += blockDim.x) {
        int f = i >> 6, k = i & 63;
        wlT[k * D + f] = wl[i];
        wrT[k * D + f] = wr[i];
    }
    __syncthreads();
    const int lane = threadIdx.x & 63;
    const int wid = threadIdx.x >> 6;
    const float blv = bl[lane];
    for (int node = blockIdx.x * 4 + wid; node < nNodes; node += gridDim.x * 4) {
        float dg = fmaxf(deg[node], 1.0f);
        float a  = agg[(size_t)node * D + lane] / dg;
        float xv = xin[(size_t)node * D + lane];
        rowA[wid][lane] = a;
        rowX[wid][lane] = xv;
        float acc = blv;
        #pragma unroll
        for (int k = 0; k < D; ++k) {
            acc = fmaf(rowA[wid][k], wlT[k * D + lane], acc);
            acc = fmaf(rowX[wid][k], wrT[k * D + lane], acc);
        }
        if (mode == 0) {
            xout[(size_t)node * D + lane] = fmaxf(acc, 0.0f);
        } else {
            float ss = acc * acc;
            #pragma unroll
            for (int off = 32; off >= 1; off >>= 1) ss += __shfl_xor(ss, off, 64);
            xout[(size_t)node * D + lane] = acc / fmaxf(sqrtf(ss), 1e-12f);
        }
    }
}

extern "C" void kernel_launch(void* const* d_in, const int* in_sizes, int n_in,
                              void* d_out, int out_size, void* d_ws, size_t ws_size,
                              hipStream_t stream) {
    const float* x   = (const float*)d_in[0];
    const float* wl0 = (const float*)d_in[1];
    const float* bl0 = (const float*)d_in[2];
    const float* wr0 = (const float*)d_in[3];
    const float* wl1 = (const float*)d_in[4];
    const float* bl1 = (const float*)d_in[5];
    const float* wr1 = (const float*)d_in[6];
    const void*  ei  = d_in[7];
    float* out = (float*)d_out;

    const int N = in_sizes[0] / D;
    const int E = in_sizes[7] / 2;
    const int NB = (N + BN - 1) / BN;
    const int EPB = (E + NBLK - 1) / NBLK;
    const int TOTAL = NB << NBLK_LOG;
    const int NPARTS = (TOTAL + SCHUNK - 1) / SCHUNK;

    char* ws = (char*)d_ws;
    size_t off = 0;
    auto alloc = [&](size_t bytes) { void* p = ws + off; off = (off + bytes + 255) & ~(size_t)255; return p; };

    // regionA: pairs (E*4) then xb (N*D*2) -- strict serial lifetimes.
    size_t regionA_bytes = (size_t)E * 4;
    if ((size_t)N * D * 2 > regionA_bytes) regionA_bytes = (size_t)N * D * 2;
    size_t need = 0;
    {
        size_t o = 0;
        auto sim = [&](size_t b) { o = (o + b + 255) & ~(size_t)255; };
        sim(4); sim(16384 * 2); sim(16384 * 2);
        sim(((size_t)MAXB << NBLK_LOG) * 4); sim(64 * 4); sim(((size_t)MAXB + 1) * 4);
        sim(((size_t)N + 1) * 4); sim((size_t)E * 4);
        sim(regionA_bytes); sim((size_t)N * D * 2); sim((size_t)N * D * 2);
        need = o;
    }

    if (ws_size >= need && NB <= MAXB && NPARTS <= 64) {
        int* flag     = (int*)alloc(4);
        unsigned short* whi = (unsigned short*)alloc(16384 * 2);
        unsigned short* wlo = (unsigned short*)alloc(16384 * 2);
        int* H        = (int*)alloc(((size_t)MAXB << NBLK_LOG) * 4);
        int* part     = (int*)alloc(64 * 4);
        int* bbase    = (int*)alloc(((size_t)MAXB + 1) * 4);
        int* rowStart = (int*)alloc(((size_t)N + 1) * 4);
        int* srcs     = (int*)alloc((size_t)E * 4);
        void* regionA = alloc(regionA_bytes);
        unsigned short* x1b  = (unsigned short*)alloc((size_t)N * D * 2);
        unsigned short* aggb = (unsigned short*)alloc((size_t)N * D * 2);
        unsigned* pairs = (unsigned*)regionA;
        unsigned short* xb = (unsigned short*)regionA;      // after bucket_to_csr

        detect_idx64<<<1, 64, 0, stream>>>((const int*)ei, flag);
        conv_w4<<<64, 256, 0, stream>>>(wl0, wr0, wl1, wr1, whi, wlo);
        hist2d<<<NBLK, 256, 0, stream>>>(ei, flag, H, E, NB, EPB);
        scan_h_partial<<<NPARTS, 256, 0, stream>>>(H, part, TOTAL);
        scan_h_mid<<<1, 64, 0, stream>>>(part, &bbase[NB], NPARTS, E);
        scan_h_final<<<NPARTS, 256, 0, stream>>>(H, part, bbase, TOTAL);
        fill2<<<NBLK, 256, 0, stream>>>(ei, flag, H, pairs, E, NB, EPB);
        bucket_to_csr<<<NB, 512, 0, stream>>>(pairs, bbase, rowStart, srcs, N, NB, E);
        conv_xbf<<<1024, 256, 0, stream>>>(x, (uint4*)xb, N * 8);   // regionA reuse

        const int gGather = (N + 31) / 32;
        const int gMfma   = (N + 127) / 128;
        // layer 0
        gather_mean_bf16<<<gGather, 256, 0, stream>>>(xb, rowStart, srcs, aggb, N);
        gemm_mfma<0><<<gMfma, 256, 0, stream>>>(aggb, x, (const unsigned short*)0,
                                                whi, wlo, bl0, (float*)0, x1b, N);
        // layer 1
        gather_mean_bf16<<<gGather, 256, 0, stream>>>(x1b, rowStart, srcs, aggb, N);
        gemm_mfma<1><<<gMfma, 256, 0, stream>>>(aggb, (const float*)0, x1b,
                                                whi + 2 * 4096, wlo + 2 * 4096, bl1,
                                                out, (unsigned short*)0, N);
    } else {
        // fallback: round-1 scatter path (~26 MB ws)
        int*   flag = (int*)alloc(4);
        float* deg  = (float*)alloc((size_t)N * 4);
        float* agg  = (float*)alloc((size_t)N * D * 4);
        float* x1   = out;  // safe: sage_update reads only its own row of xin

        detect_idx64<<<1, 64, 0, stream>>>((const int*)ei, flag);
        hipMemsetAsync(deg, 0, ((size_t)N + (size_t)N * D) * 4, stream);
        sage_scatter<<<4096, 256, 0, stream>>>(x, ei, flag, agg, deg, E, 1);
        sage_update<<<2048, 256, 0, stream>>>(x, agg, deg, wl0, bl0, wr0, x1, N, 0);
        hipMemsetAsync(agg, 0, (size_t)N * D * 4, stream);
        sage_scatter<<<4096, 256, 0, stream>>>(x1, ei, flag, agg, deg, E, 0);
        sage_update<<<2048, 256, 0, stream>>>(x1, agg, deg, wl1, bl1, wr1, out, N, 1);
    }
}

// Round 13
// 169.768 us; speedup vs baseline: 1.2946x; 1.0525x over previous
//
#include <hip/hip_runtime.h>
#include <math.h>

#define D 64
#define BSHIFT 8      // bucket = dst >> 8 (256 nodes per bucket)
#define BN 256        // nodes per bucket
#define MAXB 512      // max buckets (N <= 131072 -> src fits 20 bits)
#define NBLK 256      // partition blocks for hist2d/fill2
#define NBLK_LOG 8
#define SCHUNK 4096   // H entries per scan block (256 thr x 16)

typedef short bf16x8v __attribute__((ext_vector_type(8)));
typedef float f32x4v __attribute__((ext_vector_type(4)));

__device__ __forceinline__ unsigned short f2bf(float f) {   // round-to-nearest-even
    unsigned u = __float_as_uint(f);
    return (unsigned short)((u + 0x7FFFu + ((u >> 16) & 1u)) >> 16);
}
__device__ __forceinline__ float bf2f(unsigned short b) {
    return __uint_as_float(((unsigned)b) << 16);
}

// Fused prep: block 0 = idx64 detect; blocks [1,65) = weight hi/lo split;
// blocks [65, ...) = x f32 -> bf16 conversion (grid-stride).
__global__ __launch_bounds__(256) void prep(
        const int* __restrict__ ei, int* __restrict__ flag,
        const float* __restrict__ w0, const float* __restrict__ w1,
        const float* __restrict__ w2, const float* __restrict__ w3,
        unsigned short* __restrict__ hi, unsigned short* __restrict__ lo,
        const float* __restrict__ x, uint4* __restrict__ xb4, int total8,
        int nXbfBlocks) {
    const int b = blockIdx.x;
    if (b == 0) {
        if (threadIdx.x < 64) {
            int v = ei[2 * threadIdx.x + 1];
            unsigned long long m = __ballot(v != 0);
            if (threadIdx.x == 0) flag[0] = (m == 0ULL) ? 1 : 0;
        }
        return;
    }
    if (b < 65) {
        int i = (b - 1) * 256 + threadIdx.x;           // 0..16383
        const float* ws_[4] = {w0, w1, w2, w3};
        float f = ws_[i >> 12][i & 4095];
        unsigned short h = f2bf(f);
        hi[i] = h;
        lo[i] = f2bf(f - bf2f(h));
        return;
    }
    int i = (b - 65) * 256 + threadIdx.x;
    int stride = nXbfBlocks * 256;
    for (; i < total8; i += stride) {
        float4 u0 = *(const float4*)(x + (size_t)i * 8);
        float4 u1 = *(const float4*)(x + (size_t)i * 8 + 4);
        uint4 p;
        p.x = (unsigned)f2bf(u0.x) | ((unsigned)f2bf(u0.y) << 16);
        p.y = (unsigned)f2bf(u0.z) | ((unsigned)f2bf(u0.w) << 16);
        p.z = (unsigned)f2bf(u1.x) | ((unsigned)f2bf(u1.y) << 16);
        p.w = (unsigned)f2bf(u1.z) | ((unsigned)f2bf(u1.w) << 16);
        xb4[i] = p;
    }
}

// ---------------- deterministic counting-sort CSR build ----------------

__global__ __launch_bounds__(256) void hist2d(
        const void* __restrict__ eidx, const int* __restrict__ flagp,
        int* __restrict__ H, int nE, int nb, int epb) {
    __shared__ int h[MAXB];
    const bool idx64 = (*flagp != 0);
    const int* __restrict__ ei32 = (const int*)eidx;
    const long long* __restrict__ ei64 = (const long long*)eidx;
    for (int i = threadIdx.x; i < nb; i += 256) h[i] = 0;
    __syncthreads();
    const int e0 = blockIdx.x * epb;
    const int e1 = min(e0 + epb, nE);
    for (int e = e0 + threadIdx.x; e < e1; e += 256) {
        int d = idx64 ? (int)ei64[e + nE] : ei32[e + nE];
        atomicAdd(&h[d >> BSHIFT], 1);
    }
    __syncthreads();
    for (int i = threadIdx.x; i < nb; i += 256)
        H[(i << NBLK_LOG) + blockIdx.x] = h[i];
}

__global__ __launch_bounds__(256) void scan_h_partial(
        const int* __restrict__ H, int* __restrict__ part, int total) {
    __shared__ int red[4];
    int base = blockIdx.x * SCHUNK + threadIdx.x * 16;
    int s = 0;
    #pragma unroll
    for (int k = 0; k < 16; ++k) { int i = base + k; if (i < total) s += H[i]; }
    #pragma unroll
    for (int off = 32; off >= 1; off >>= 1) s += __shfl_xor(s, off, 64);
    int lane = threadIdx.x & 63, wid = threadIdx.x >> 6;
    if (lane == 0) red[wid] = s;
    __syncthreads();
    if (threadIdx.x == 0) part[blockIdx.x] = red[0] + red[1] + red[2] + red[3];
}

__global__ void scan_h_mid(int* __restrict__ part, int* __restrict__ bbaseN,
                           int nParts, int nE) {
    int tid = threadIdx.x;
    int v = (tid < nParts) ? part[tid] : 0;
    int x = v;
    #pragma unroll
    for (int off = 1; off < 64; off <<= 1) { int y = __shfl_up(x, off, 64); if (tid >= off) x += y; }
    if (tid < nParts) part[tid] = x - v;
    if (tid == 0) bbaseN[0] = nE;
}

__global__ __launch_bounds__(256) void scan_h_final(
        int* __restrict__ H, const int* __restrict__ part,
        int* __restrict__ bbase, int total) {
    __shared__ int wtot[4];
    int tid = threadIdx.x, lane = tid & 63, wid = tid >> 6;
    int base = blockIdx.x * SCHUNK + tid * 16;
    int v[16]; int t = 0;
    #pragma unroll
    for (int k = 0; k < 16; ++k) { int i = base + k; v[k] = (i < total) ? H[i] : 0; t += v[k]; }
    int x = t;
    #pragma unroll
    for (int off = 1; off < 64; off <<= 1) { int y = __shfl_up(x, off, 64); if (lane >= off) x += y; }
    if (lane == 63) wtot[wid] = x;
    __syncthreads();
    int woff = 0;
    for (int w = 0; w < wid; ++w) woff += wtot[w];
    int run = part[blockIdx.x] + woff + (x - t);
    #pragma unroll
    for (int k = 0; k < 16; ++k) {
        int i = base + k;
        if (i < total) {
            H[i] = run;
            if ((i & (NBLK - 1)) == 0) bbase[i >> NBLK_LOG] = run;
            run += v[k];
        }
    }
}

// Packed 4-B pairs: src (bits 0..19) | local-dst (bits 20..27).
__global__ __launch_bounds__(256) void fill2(
        const void* __restrict__ eidx, const int* __restrict__ flagp,
        const int* __restrict__ H, unsigned* __restrict__ pairs,
        int nE, int nb, int epb) {
    __shared__ int cur[MAXB];
    const bool idx64 = (*flagp != 0);
    const int* __restrict__ ei32 = (const int*)eidx;
    const long long* __restrict__ ei64 = (const long long*)eidx;
    for (int i = threadIdx.x; i < nb; i += 256)
        cur[i] = H[(i << NBLK_LOG) + blockIdx.x];
    __syncthreads();
    const int e0 = blockIdx.x * epb;
    const int e1 = min(e0 + epb, nE);
    for (int e = e0 + threadIdx.x; e < e1; e += 256) {
        int s, d;
        if (idx64) { s = (int)ei64[e]; d = (int)ei64[e + nE]; }
        else       { s = ei32[e];      d = ei32[e + nE]; }
        int pos = atomicAdd(&cur[d >> BSHIFT], 1);
        pairs[pos] = (unsigned)s | ((unsigned)(d & (BN - 1)) << 20);
    }
}

// One block (256 thr) per bucket of 256 nodes.
__global__ __launch_bounds__(256) void bucket_to_csr(
        const unsigned* __restrict__ pairs,
        const int* __restrict__ bbase,
        int* __restrict__ rowStart, int* __restrict__ srcs,
        int N, int nb, int nE) {
    __shared__ int lcnt[BN];
    __shared__ int lcur[BN];
    __shared__ int wtot[4];
    const int b = blockIdx.x;
    const int base = bbase[b];
    const int cnt  = bbase[b + 1] - base;
    const int tid = threadIdx.x, lane = tid & 63, wid = tid >> 6;
    lcnt[tid] = 0;
    __syncthreads();
    for (int i = tid; i < cnt; i += 256)
        atomicAdd(&lcnt[(int)(pairs[base + i] >> 20)], 1);
    __syncthreads();
    int v = lcnt[tid];
    int x = v;
    #pragma unroll
    for (int off = 1; off < 64; off <<= 1) { int y = __shfl_up(x, off, 64); if (lane >= off) x += y; }
    if (lane == 63) wtot[wid] = x;
    __syncthreads();
    if (tid == 0) {
        int r = 0;
        for (int w = 0; w < 4; ++w) { int t = wtot[w]; wtot[w] = r; r += t; }
    }
    __syncthreads();
    int excl = wtot[wid] + (x - v);
    lcur[tid] = excl;
    int node = b * BN + tid;
    if (node < N) rowStart[node] = base + excl;
    if (b == nb - 1 && tid == 0) rowStart[N] = nE;
    __syncthreads();
    for (int i = tid; i < cnt; i += 256) {
        unsigned p = pairs[base + i];
        int pos = atomicAdd(&lcur[(int)(p >> 20)], 1);
        srcs[base + pos] = (int)(p & 0xFFFFFu);
    }
}

// ---------------- layer stage 1: gather + mean (bf16 in, bf16 out) ---------
// 8 lanes per node, 32 nodes/block, unroll 8 -> deep row-load pipeline.
#define UNPK8(v, arr)                                                     \
    do {                                                                  \
        arr[0] += __uint_as_float((v).x << 16);                           \
        arr[1] += __uint_as_float((v).x & 0xFFFF0000u);                   \
        arr[2] += __uint_as_float((v).y << 16);                           \
        arr[3] += __uint_as_float((v).y & 0xFFFF0000u);                   \
        arr[4] += __uint_as_float((v).z << 16);                           \
        arr[5] += __uint_as_float((v).z & 0xFFFF0000u);                   \
        arr[6] += __uint_as_float((v).w << 16);                           \
        arr[7] += __uint_as_float((v).w & 0xFFFF0000u);                   \
    } while (0)

__global__ __launch_bounds__(256) void gather_mean_bf16(
        const unsigned short* __restrict__ xb,
        const int* __restrict__ rowStart,
        const int* __restrict__ srcs,
        unsigned short* __restrict__ aggb,
        int nNodes) {
    const int tid = threadIdx.x;
    const int gl = tid & 7;
    const int grp = tid >> 3;
    const int node = blockIdx.x * 32 + grp;
    if (node >= nNodes) return;
    const int r0 = rowStart[node], r1 = rowStart[node + 1];
    float a[8] = {0.f,0.f,0.f,0.f,0.f,0.f,0.f,0.f};
    const unsigned short* xp = xb + gl * 8;
    int j = r0;
    for (; j + 8 <= r1; j += 8) {
        uint4 v0 = *(const uint4*)(xp + (size_t)srcs[j    ] * D);
        uint4 v1 = *(const uint4*)(xp + (size_t)srcs[j + 1] * D);
        uint4 v2 = *(const uint4*)(xp + (size_t)srcs[j + 2] * D);
        uint4 v3 = *(const uint4*)(xp + (size_t)srcs[j + 3] * D);
        uint4 v4 = *(const uint4*)(xp + (size_t)srcs[j + 4] * D);
        uint4 v5 = *(const uint4*)(xp + (size_t)srcs[j + 5] * D);
        uint4 v6 = *(const uint4*)(xp + (size_t)srcs[j + 6] * D);
        uint4 v7 = *(const uint4*)(xp + (size_t)srcs[j + 7] * D);
        UNPK8(v0, a); UNPK8(v1, a); UNPK8(v2, a); UNPK8(v3, a);
        UNPK8(v4, a); UNPK8(v5, a); UNPK8(v6, a); UNPK8(v7, a);
    }
    if (j + 4 <= r1) {
        uint4 v0 = *(const uint4*)(xp + (size_t)srcs[j    ] * D);
        uint4 v1 = *(const uint4*)(xp + (size_t)srcs[j + 1] * D);
        uint4 v2 = *(const uint4*)(xp + (size_t)srcs[j + 2] * D);
        uint4 v3 = *(const uint4*)(xp + (size_t)srcs[j + 3] * D);
        UNPK8(v0, a); UNPK8(v1, a); UNPK8(v2, a); UNPK8(v3, a);
        j += 4;
    }
    if (j + 2 <= r1) {
        uint4 v0 = *(const uint4*)(xp + (size_t)srcs[j    ] * D);
        uint4 v1 = *(const uint4*)(xp + (size_t)srcs[j + 1] * D);
        UNPK8(v0, a); UNPK8(v1, a);
        j += 2;
    }
    if (j < r1) {
        uint4 v = *(const uint4*)(xp + (size_t)srcs[j] * D);
        UNPK8(v, a);
    }
    const float inv = 1.0f / fmaxf((float)(r1 - r0), 1.0f);
    uint4 p;
    p.x = (unsigned)f2bf(a[0]*inv) | ((unsigned)f2bf(a[1]*inv) << 16);
    p.y = (unsigned)f2bf(a[2]*inv) | ((unsigned)f2bf(a[3]*inv) << 16);
    p.z = (unsigned)f2bf(a[4]*inv) | ((unsigned)f2bf(a[5]*inv) << 16);
    p.w = (unsigned)f2bf(a[6]*inv) | ((unsigned)f2bf(a[7]*inv) << 16);
    *(uint4*)(aggb + (size_t)node * D + gl * 8) = p;
}

// ---------------- layer stage 2: bf16 MFMA GEMM, 2 tiles/wave --------------
// All A inputs bf16 (aggb neighbor mean + xin self); weights hi+lo split.
// 64 MFMAs/wave. LAYER 0: ReLU -> bf16 outb. LAYER 1: L2-normalize -> f32 outf.
template<int LAYER>
__global__ __launch_bounds__(256) void gemm_mfma(
        const unsigned short* __restrict__ aggb,
        const unsigned short* __restrict__ xin,
        const unsigned short* __restrict__ wHi,
        const unsigned short* __restrict__ wLo,
        const float* __restrict__ bl,
        float* __restrict__ outf,
        unsigned short* __restrict__ outb,
        int nNodes) {
    const int l = threadIdx.x & 63;
    const int wv = threadIdx.x >> 6;
    const int col = l & 15, grp = l >> 4;
    const int base0 = blockIdx.x * 128 + wv * 32;
    if (base0 >= nNodes) return;

    // ---- A frags for both tiles (all global loads issued up front) ----
    bf16x8v gH[2][2], sH[2][2];   // [tile][h]
    #pragma unroll
    for (int tt = 0; tt < 2; ++tt) {
        const int anode = min(base0 + tt * 16 + col, nNodes - 1);
        #pragma unroll
        for (int h = 0; h < 2; ++h) {
            gH[tt][h] = *(const bf16x8v*)(aggb + (size_t)anode * D + h * 32 + grp * 8);
            sH[tt][h] = *(const bf16x8v*)(xin  + (size_t)anode * D + h * 32 + grp * 8);
        }
    }

    // ---- MFMA: weight frags loaded once per (t,h), used by both tiles ----
    f32x4v acc[2][4];
    #pragma unroll
    for (int tt = 0; tt < 2; ++tt)
        #pragma unroll
        for (int t = 0; t < 4; ++t) acc[tt][t] = (f32x4v){0.f, 0.f, 0.f, 0.f};

    #pragma unroll
    for (int t = 0; t < 4; ++t) {
        const unsigned short* whl = wHi + (size_t)(t * 16 + col) * D;
        const unsigned short* wol = wLo + (size_t)(t * 16 + col) * D;
        const unsigned short* whr = whl + 4096;
        const unsigned short* wor = wol + 4096;
        #pragma unroll
        for (int h = 0; h < 2; ++h) {
            const int k0 = h * 32 + grp * 8;
            bf16x8v bh  = *(const bf16x8v*)(whl + k0);
            bf16x8v bo  = *(const bf16x8v*)(wol + k0);
            bf16x8v bh2 = *(const bf16x8v*)(whr + k0);
            bf16x8v bo2 = *(const bf16x8v*)(wor + k0);
            #pragma unroll
            for (int tt = 0; tt < 2; ++tt) {
                acc[tt][t] = __builtin_amdgcn_mfma_f32_16x16x32_bf16(gH[tt][h], bh,  acc[tt][t], 0, 0, 0);
                acc[tt][t] = __builtin_amdgcn_mfma_f32_16x16x32_bf16(gH[tt][h], bo,  acc[tt][t], 0, 0, 0);
                acc[tt][t] = __builtin_amdgcn_mfma_f32_16x16x32_bf16(sH[tt][h], bh2, acc[tt][t], 0, 0, 0);
                acc[tt][t] = __builtin_amdgcn_mfma_f32_16x16x32_bf16(sH[tt][h], bo2, acc[tt][t], 0, 0, 0);
            }
        }
    }

    // ---- epilogue per tile ----
    #pragma unroll
    for (int tt = 0; tt < 2; ++tt) {
        const int base = base0 + tt * 16;
        #pragma unroll
        for (int t = 0; t < 4; ++t) {
            float b = bl[t * 16 + col];
            #pragma unroll
            for (int r = 0; r < 4; ++r) acc[tt][t][r] += b;
        }
        if (LAYER == 0) {
            #pragma unroll
            for (int t = 0; t < 4; ++t)
                #pragma unroll
                for (int r = 0; r < 4; ++r) {
                    int n = base + grp * 4 + r;
                    if (n < nNodes)
                        outb[(size_t)n * D + t * 16 + col] = f2bf(fmaxf(acc[tt][t][r], 0.f));
                }
        } else {
            float ss[4] = {0.f, 0.f, 0.f, 0.f};
            #pragma unroll
            for (int t = 0; t < 4; ++t)
                #pragma unroll
                for (int r = 0; r < 4; ++r) ss[r] += acc[tt][t][r] * acc[tt][t][r];
            #pragma unroll
            for (int r = 0; r < 4; ++r) {
                #pragma unroll
                for (int off = 1; off < 16; off <<= 1) ss[r] += __shfl_xor(ss[r], off, 64);
            }
            float inv[4];
            #pragma unroll
            for (int r = 0; r < 4; ++r) inv[r] = 1.0f / fmaxf(sqrtf(ss[r]), 1e-12f);
            #pragma unroll
            for (int t = 0; t < 4; ++t)
                #pragma unroll
                for (int r = 0; r < 4; ++r) {
                    int n = base + grp * 4 + r;
                    if (n < nNodes)
                        outf[(size_t)n * D + t * 16 + col] = acc[tt][t][r] * inv[r];
                }
        }
    }
}

// ---------------- fallback: atomic scatter path (ws too small) -------------

__global__ void detect_idx64(const int* __restrict__ ei, int* __restrict__ flag) {
    int v = ei[2 * threadIdx.x + 1];
    unsigned long long b = __ballot(v != 0);
    if (threadIdx.x == 0) flag[0] = (b == 0ULL) ? 1 : 0;
}

__global__ __launch_bounds__(256) void sage_scatter(
        const float* __restrict__ x,
        const void* __restrict__ eidx,
        const int* __restrict__ flagp,
        float* __restrict__ agg,
        float* __restrict__ deg,
        int nE, int doDeg) {
    const bool idx64 = (*flagp != 0);
    const int lane = threadIdx.x & 63;
    int wave = (int)((blockIdx.x * blockDim.x + threadIdx.x) >> 6);
    const int waveStride = (int)((gridDim.x * blockDim.x) >> 6);
    const int* __restrict__ ei32 = (const int*)eidx;
    const long long* __restrict__ ei64 = (const long long*)eidx;
    for (int e = wave; e < nE; e += waveStride) {
        int s, d;
        if (idx64) { s = (int)ei64[e]; d = (int)ei64[e + nE]; }
        else       { s = ei32[e];      d = ei32[e + nE]; }
        atomicAdd(&agg[(size_t)d * D + lane], x[(size_t)s * D + lane]);
        if (doDeg && lane == 0) atomicAdd(&deg[d], 1.0f);
    }
}

__global__ __launch_bounds__(256) void sage_update(
        const float* __restrict__ xin,
        const float* __restrict__ agg,
        const float* __restrict__ deg,
        const float* __restrict__ wl,
        const float* __restrict__ bl,
        const float* __restrict__ wr,
        float* __restrict__ xout,
        int nNodes, int mode) {
    __shared__ float wlT[D * D];
    __shared__ float wrT[D * D];
    __shared__ float rowA[4][D];
    __shared__ float rowX[4][D];
    for (int i = threadIdx.x; i < D * D; i += blockDim.x) {
        int f = i >> 6, k = i & 63;
        wlT[k * D + f] = wl[i];
        wrT[k * D + f] = wr[i];
    }
    __syncthreads();
    const int lane = threadIdx.x & 63;
    const int wid = threadIdx.x >> 6;
    const float blv = bl[lane];
    for (int node = blockIdx.x * 4 + wid; node < nNodes; node += gridDim.x * 4) {
        float dg = fmaxf(deg[node], 1.0f);
        float a  = agg[(size_t)node * D + lane] / dg;
        float xv = xin[(size_t)node * D + lane];
        rowA[wid][lane] = a;
        rowX[wid][lane] = xv;
        float acc = blv;
        #pragma unroll
        for (int k = 0; k < D; ++k) {
            acc = fmaf(rowA[wid][k], wlT[k * D + lane], acc);
            acc = fmaf(rowX[wid][k], wrT[k * D + lane], acc);
        }
        if (mode == 0) {
            xout[(size_t)node * D + lane] = fmaxf(acc, 0.0f);
        } else {
            float ss = acc * acc;
            #pragma unroll
            for (int off = 32; off >= 1; off >>= 1) ss += __shfl_xor(ss, off, 64);
            xout[(size_t)node * D + lane] = acc / fmaxf(sqrtf(ss), 1e-12f);
        }
    }
}

extern "C" void kernel_launch(void* const* d_in, const int* in_sizes, int n_in,
                              void* d_out, int out_size, void* d_ws, size_t ws_size,
                              hipStream_t stream) {
    const float* x   = (const float*)d_in[0];
    const float* wl0 = (const float*)d_in[1];
    const float* bl0 = (const float*)d_in[2];
    const float* wr0 = (const float*)d_in[3];
    const float* wl1 = (const float*)d_in[4];
    const float* bl1 = (const float*)d_in[5];
    const float* wr1 = (const float*)d_in[6];
    const void*  ei  = d_in[7];
    float* out = (float*)d_out;

    const int N = in_sizes[0] / D;
    const int E = in_sizes[7] / 2;
    const int NB = (N + BN - 1) / BN;        // 391 for N=100000
    const int EPB = (E + NBLK - 1) / NBLK;
    const int TOTAL = NB << NBLK_LOG;
    const int NPARTS = (TOTAL + SCHUNK - 1) / SCHUNK;   // 25 for N=100000

    char* ws = (char*)d_ws;
    size_t off = 0;
    auto alloc = [&](size_t bytes) { void* p = ws + off; off = (off + bytes + 255) & ~(size_t)255; return p; };

    size_t need = 0;
    {
        size_t o = 0;
        auto sim = [&](size_t b) { o = (o + b + 255) & ~(size_t)255; };
        sim(4); sim(16384 * 2); sim(16384 * 2);
        sim(((size_t)MAXB << NBLK_LOG) * 4); sim(64 * 4); sim(((size_t)MAXB + 1) * 4);
        sim(((size_t)N + 1) * 4); sim((size_t)E * 4); sim((size_t)E * 4);
        sim((size_t)N * D * 2); sim((size_t)N * D * 2); sim((size_t)N * D * 2);
        need = o;
    }

    if (ws_size >= need && NB <= MAXB && NPARTS <= 64) {
        int* flag     = (int*)alloc(4);
        unsigned short* whi = (unsigned short*)alloc(16384 * 2);
        unsigned short* wlo = (unsigned short*)alloc(16384 * 2);
        int* H        = (int*)alloc(((size_t)MAXB << NBLK_LOG) * 4);
        int* part     = (int*)alloc(64 * 4);
        int* bbase    = (int*)alloc(((size_t)MAXB + 1) * 4);
        int* rowStart = (int*)alloc(((size_t)N + 1) * 4);
        int* srcs     = (int*)alloc((size_t)E * 4);
        unsigned* pairs = (unsigned*)alloc((size_t)E * 4);
        unsigned short* xb   = (unsigned short*)alloc((size_t)N * D * 2);
        unsigned short* x1b  = (unsigned short*)alloc((size_t)N * D * 2);
        unsigned short* aggb = (unsigned short*)alloc((size_t)N * D * 2);

        const int nXbf = 1024;
        prep<<<65 + nXbf, 256, 0, stream>>>((const int*)ei, flag,
                                            wl0, wr0, wl1, wr1, whi, wlo,
                                            x, (uint4*)xb, N * 8, nXbf);
        hist2d<<<NBLK, 256, 0, stream>>>(ei, flag, H, E, NB, EPB);
        scan_h_partial<<<NPARTS, 256, 0, stream>>>(H, part, TOTAL);
        scan_h_mid<<<1, 64, 0, stream>>>(part, &bbase[NB], NPARTS, E);
        scan_h_final<<<NPARTS, 256, 0, stream>>>(H, part, bbase, TOTAL);
        fill2<<<NBLK, 256, 0, stream>>>(ei, flag, H, pairs, E, NB, EPB);
        bucket_to_csr<<<NB, 256, 0, stream>>>(pairs, bbase, rowStart, srcs, N, NB, E);

        const int gGather = (N + 31) / 32;
        const int gMfma   = (N + 127) / 128;
        // layer 0
        gather_mean_bf16<<<gGather, 256, 0, stream>>>(xb, rowStart, srcs, aggb, N);
        gemm_mfma<0><<<gMfma, 256, 0, stream>>>(aggb, xb, whi, wlo, bl0,
                                                (float*)0, x1b, N);
        // layer 1
        gather_mean_bf16<<<gGather, 256, 0, stream>>>(x1b, rowStart, srcs, aggb, N);
        gemm_mfma<1><<<gMfma, 256, 0, stream>>>(aggb, x1b, whi + 2 * 4096, wlo + 2 * 4096,
                                                bl1, out, (unsigned short*)0, N);
    } else {
        // fallback: round-1 scatter path (~26 MB ws)
        int*   flag = (int*)alloc(4);
        float* deg  = (float*)alloc((size_t)N * 4);
        float* agg  = (float*)alloc((size_t)N * D * 4);
        float* x1   = out;  // safe: sage_update reads only its own row of xin

        detect_idx64<<<1, 64, 0, stream>>>((const int*)ei, flag);
        hipMemsetAsync(deg, 0, ((size_t)N + (size_t)N * D) * 4, stream);
        sage_scatter<<<4096, 256, 0, stream>>>(x, ei, flag, agg, deg, E, 1);
        sage_update<<<2048, 256, 0, stream>>>(x, agg, deg, wl0, bl0, wr0, x1, N, 0);
        hipMemsetAsync(agg, 0, (size_t)N * D * 4, stream);
        sage_scatter<<<4096, 256, 0, stream>>>(x1, ei, flag, agg, deg, E, 0);
        sage_update<<<2048, 256, 0, stream>>>(x1, agg, deg, wl1, bl1, wr1, out, N, 1);
    }
}

// Round 14
// 153.495 us; speedup vs baseline: 1.4319x; 1.1060x over previous
//
#include <hip/hip_runtime.h>
#include <math.h>

#define D 64
#define BSHIFT 8      // bucket = dst >> 8 (256 nodes per bucket)
#define BN 256        // nodes per bucket
#define MAXB 512      // max buckets (N <= 131072 -> src fits 20 bits)
#define NBLK 256      // partition blocks for hist/fill2
#define NBLK_LOG 8
#define SCHUNK 4096   // H entries per scan block (256 thr x 16)
#define NXBF 1024     // conversion blocks inside prep_hist

typedef short bf16x8v __attribute__((ext_vector_type(8)));
typedef float f32x4v __attribute__((ext_vector_type(4)));

__device__ __forceinline__ unsigned short f2bf(float f) {   // round-to-nearest-even
    unsigned u = __float_as_uint(f);
    return (unsigned short)((u + 0x7FFFu + ((u >> 16) & 1u)) >> 16);
}
__device__ __forceinline__ float bf2f(unsigned short b) {
    return __uint_as_float(((unsigned)b) << 16);
}

// Per-wave inline int64-vs-int32 detection: all lanes read the same 64 odd
// words (L2-hot after the first block); ballot==0 -> int64 hi-halves.
__device__ __forceinline__ bool is_idx64(const int* __restrict__ ei32) {
    int v = ei32[2 * (threadIdx.x & 63) + 1];
    return __ballot(v != 0) == 0ULL;
}

// Fused prep: blocks [0,64) = weight hi/lo split; [64,64+NXBF) = x->bf16;
// [64+NXBF, 64+NXBF+NBLK) = edge histogram (H[bucket][blk]).
__global__ __launch_bounds__(256) void prep_hist(
        const float* __restrict__ w0, const float* __restrict__ w1,
        const float* __restrict__ w2, const float* __restrict__ w3,
        unsigned short* __restrict__ hi, unsigned short* __restrict__ lo,
        const float* __restrict__ x, uint4* __restrict__ xb4, int total8,
        const void* __restrict__ eidx, int* __restrict__ H,
        int nE, int nb, int epb) {
    const int b = blockIdx.x;
    if (b < 64) {
        int i = b * 256 + threadIdx.x;                 // 0..16383
        const float* ws_[4] = {w0, w1, w2, w3};
        float f = ws_[i >> 12][i & 4095];
        unsigned short h = f2bf(f);
        hi[i] = h;
        lo[i] = f2bf(f - bf2f(h));
        return;
    }
    if (b < 64 + NXBF) {
        int i = (b - 64) * 256 + threadIdx.x;
        int stride = NXBF * 256;
        for (; i < total8; i += stride) {
            float4 u0 = *(const float4*)(x + (size_t)i * 8);
            float4 u1 = *(const float4*)(x + (size_t)i * 8 + 4);
            uint4 p;
            p.x = (unsigned)f2bf(u0.x) | ((unsigned)f2bf(u0.y) << 16);
            p.y = (unsigned)f2bf(u0.z) | ((unsigned)f2bf(u0.w) << 16);
            p.z = (unsigned)f2bf(u1.x) | ((unsigned)f2bf(u1.y) << 16);
            p.w = (unsigned)f2bf(u1.z) | ((unsigned)f2bf(u1.w) << 16);
            xb4[i] = p;
        }
        return;
    }
    // ---- histogram part ----
    __shared__ int h[MAXB];
    const int hb = b - (64 + NXBF);
    const int* __restrict__ ei32 = (const int*)eidx;
    const long long* __restrict__ ei64 = (const long long*)eidx;
    const bool idx64 = is_idx64(ei32);
    for (int i = threadIdx.x; i < nb; i += 256) h[i] = 0;
    __syncthreads();
    const int e0 = hb * epb;
    const int e1 = min(e0 + epb, nE);
    for (int e = e0 + threadIdx.x; e < e1; e += 256) {
        int d = idx64 ? (int)ei64[e + nE] : ei32[e + nE];
        atomicAdd(&h[d >> BSHIFT], 1);
    }
    __syncthreads();
    for (int i = threadIdx.x; i < nb; i += 256)
        H[(i << NBLK_LOG) + hb] = h[i];
}

// ---------------- deterministic counting-sort CSR build ----------------

__global__ __launch_bounds__(256) void scan_h_partial(
        const int* __restrict__ H, int* __restrict__ part, int total) {
    __shared__ int red[4];
    int base = blockIdx.x * SCHUNK + threadIdx.x * 16;
    int s = 0;
    #pragma unroll
    for (int k = 0; k < 16; ++k) { int i = base + k; if (i < total) s += H[i]; }
    #pragma unroll
    for (int off = 32; off >= 1; off >>= 1) s += __shfl_xor(s, off, 64);
    int lane = threadIdx.x & 63, wid = threadIdx.x >> 6;
    if (lane == 0) red[wid] = s;
    __syncthreads();
    if (threadIdx.x == 0) part[blockIdx.x] = red[0] + red[1] + red[2] + red[3];
}

// Folds the mid-scan: each block wave-scans raw part[] (<=64 entries) and
// shuffles out its own exclusive offset. Writes exclusive positions back to
// H, bucket bases to bbase, and bbase[nb] = E.
__global__ __launch_bounds__(256) void scan_h_final(
        int* __restrict__ H, const int* __restrict__ part,
        int* __restrict__ bbase, int total, int nParts, int nb, int nE) {
    __shared__ int wtot[4];
    int tid = threadIdx.x, lane = tid & 63, wid = tid >> 6;
    // inline exclusive block offset from raw partials
    int pv = (lane < nParts) ? part[lane] : 0;
    int px = pv;
    #pragma unroll
    for (int off = 1; off < 64; off <<= 1) { int y = __shfl_up(px, off, 64); if (lane >= off) px += y; }
    int blockOff = (blockIdx.x == 0) ? 0 : __shfl(px, blockIdx.x - 1, 64);

    int base = blockIdx.x * SCHUNK + tid * 16;
    int v[16]; int t = 0;
    #pragma unroll
    for (int k = 0; k < 16; ++k) { int i = base + k; v[k] = (i < total) ? H[i] : 0; t += v[k]; }
    int x = t;
    #pragma unroll
    for (int off = 1; off < 64; off <<= 1) { int y = __shfl_up(x, off, 64); if (lane >= off) x += y; }
    if (lane == 63) wtot[wid] = x;
    __syncthreads();
    int woff = 0;
    for (int w = 0; w < wid; ++w) woff += wtot[w];
    int run = blockOff + woff + (x - t);
    #pragma unroll
    for (int k = 0; k < 16; ++k) {
        int i = base + k;
        if (i < total) {
            H[i] = run;
            if ((i & (NBLK - 1)) == 0) bbase[i >> NBLK_LOG] = run;
            run += v[k];
        }
    }
    if (blockIdx.x == 0 && tid == 0) bbase[nb] = nE;
}

// Packed 4-B pairs: src (bits 0..19) | local-dst (bits 20..27).
__global__ __launch_bounds__(256) void fill2(
        const void* __restrict__ eidx,
        const int* __restrict__ H, unsigned* __restrict__ pairs,
        int nE, int nb, int epb) {
    __shared__ int cur[MAXB];
    const int* __restrict__ ei32 = (const int*)eidx;
    const long long* __restrict__ ei64 = (const long long*)eidx;
    const bool idx64 = is_idx64(ei32);
    for (int i = threadIdx.x; i < nb; i += 256)
        cur[i] = H[(i << NBLK_LOG) + blockIdx.x];
    __syncthreads();
    const int e0 = blockIdx.x * epb;
    const int e1 = min(e0 + epb, nE);
    for (int e = e0 + threadIdx.x; e < e1; e += 256) {
        int s, d;
        if (idx64) { s = (int)ei64[e]; d = (int)ei64[e + nE]; }
        else       { s = ei32[e];      d = ei32[e + nE]; }
        int pos = atomicAdd(&cur[d >> BSHIFT], 1);
        pairs[pos] = (unsigned)s | ((unsigned)(d & (BN - 1)) << 20);
    }
}

// One block (256 thr) per bucket of 256 nodes.
__global__ __launch_bounds__(256) void bucket_to_csr(
        const unsigned* __restrict__ pairs,
        const int* __restrict__ bbase,
        int* __restrict__ rowStart, int* __restrict__ srcs,
        int N, int nb, int nE) {
    __shared__ int lcnt[BN];
    __shared__ int lcur[BN];
    __shared__ int wtot[4];
    const int b = blockIdx.x;
    const int base = bbase[b];
    const int cnt  = bbase[b + 1] - base;
    const int tid = threadIdx.x, lane = tid & 63, wid = tid >> 6;
    lcnt[tid] = 0;
    __syncthreads();
    for (int i = tid; i < cnt; i += 256)
        atomicAdd(&lcnt[(int)(pairs[base + i] >> 20)], 1);
    __syncthreads();
    int v = lcnt[tid];
    int x = v;
    #pragma unroll
    for (int off = 1; off < 64; off <<= 1) { int y = __shfl_up(x, off, 64); if (lane >= off) x += y; }
    if (lane == 63) wtot[wid] = x;
    __syncthreads();
    if (tid == 0) {
        int r = 0;
        for (int w = 0; w < 4; ++w) { int t = wtot[w]; wtot[w] = r; r += t; }
    }
    __syncthreads();
    int excl = wtot[wid] + (x - v);
    lcur[tid] = excl;
    int node = b * BN + tid;
    if (node < N) rowStart[node] = base + excl;
    if (b == nb - 1 && tid == 0) rowStart[N] = nE;
    __syncthreads();
    for (int i = tid; i < cnt; i += 256) {
        unsigned p = pairs[base + i];
        int pos = atomicAdd(&lcur[(int)(p >> 20)], 1);
        srcs[base + pos] = (int)(p & 0xFFFFFu);
    }
}

// ---------------- layer stage 1: gather + mean (bf16 in, bf16 out) ---------
#define UNPK8(v, arr)                                                     \
    do {                                                                  \
        arr[0] += __uint_as_float((v).x << 16);                           \
        arr[1] += __uint_as_float((v).x & 0xFFFF0000u);                   \
        arr[2] += __uint_as_float((v).y << 16);                           \
        arr[3] += __uint_as_float((v).y & 0xFFFF0000u);                   \
        arr[4] += __uint_as_float((v).z << 16);                           \
        arr[5] += __uint_as_float((v).z & 0xFFFF0000u);                   \
        arr[6] += __uint_as_float((v).w << 16);                           \
        arr[7] += __uint_as_float((v).w & 0xFFFF0000u);                   \
    } while (0)

__global__ __launch_bounds__(256) void gather_mean_bf16(
        const unsigned short* __restrict__ xb,
        const int* __restrict__ rowStart,
        const int* __restrict__ srcs,
        unsigned short* __restrict__ aggb,
        int nNodes) {
    const int tid = threadIdx.x;
    const int gl = tid & 7;
    const int grp = tid >> 3;
    const int node = blockIdx.x * 32 + grp;
    if (node >= nNodes) return;
    const int r0 = rowStart[node], r1 = rowStart[node + 1];
    float a[8] = {0.f,0.f,0.f,0.f,0.f,0.f,0.f,0.f};
    const unsigned short* xp = xb + gl * 8;
    int j = r0;
    for (; j + 8 <= r1; j += 8) {
        uint4 v0 = *(const uint4*)(xp + (size_t)srcs[j    ] * D);
        uint4 v1 = *(const uint4*)(xp + (size_t)srcs[j + 1] * D);
        uint4 v2 = *(const uint4*)(xp + (size_t)srcs[j + 2] * D);
        uint4 v3 = *(const uint4*)(xp + (size_t)srcs[j + 3] * D);
        uint4 v4 = *(const uint4*)(xp + (size_t)srcs[j + 4] * D);
        uint4 v5 = *(const uint4*)(xp + (size_t)srcs[j + 5] * D);
        uint4 v6 = *(const uint4*)(xp + (size_t)srcs[j + 6] * D);
        uint4 v7 = *(const uint4*)(xp + (size_t)srcs[j + 7] * D);
        UNPK8(v0, a); UNPK8(v1, a); UNPK8(v2, a); UNPK8(v3, a);
        UNPK8(v4, a); UNPK8(v5, a); UNPK8(v6, a); UNPK8(v7, a);
    }
    if (j + 4 <= r1) {
        uint4 v0 = *(const uint4*)(xp + (size_t)srcs[j    ] * D);
        uint4 v1 = *(const uint4*)(xp + (size_t)srcs[j + 1] * D);
        uint4 v2 = *(const uint4*)(xp + (size_t)srcs[j + 2] * D);
        uint4 v3 = *(const uint4*)(xp + (size_t)srcs[j + 3] * D);
        UNPK8(v0, a); UNPK8(v1, a); UNPK8(v2, a); UNPK8(v3, a);
        j += 4;
    }
    if (j + 2 <= r1) {
        uint4 v0 = *(const uint4*)(xp + (size_t)srcs[j    ] * D);
        uint4 v1 = *(const uint4*)(xp + (size_t)srcs[j + 1] * D);
        UNPK8(v0, a); UNPK8(v1, a);
        j += 2;
    }
    if (j < r1) {
        uint4 v = *(const uint4*)(xp + (size_t)srcs[j] * D);
        UNPK8(v, a);
    }
    const float inv = 1.0f / fmaxf((float)(r1 - r0), 1.0f);
    uint4 p;
    p.x = (unsigned)f2bf(a[0]*inv) | ((unsigned)f2bf(a[1]*inv) << 16);
    p.y = (unsigned)f2bf(a[2]*inv) | ((unsigned)f2bf(a[3]*inv) << 16);
    p.z = (unsigned)f2bf(a[4]*inv) | ((unsigned)f2bf(a[5]*inv) << 16);
    p.w = (unsigned)f2bf(a[6]*inv) | ((unsigned)f2bf(a[7]*inv) << 16);
    *(uint4*)(aggb + (size_t)node * D + gl * 8) = p;
}

// ---------------- layer stage 2: bf16 MFMA GEMM, 4 tiles/wave --------------
// Each wave: 64 nodes (4 tiles of 16). All 16 A-loads issued up front;
// weight frags loaded once per (t,h), reused by 4 tiles (128 MFMAs/wave).
template<int LAYER>
__global__ __launch_bounds__(256) void gemm_mfma(
        const unsigned short* __restrict__ aggb,
        const unsigned short* __restrict__ xin,
        const unsigned short* __restrict__ wHi,
        const unsigned short* __restrict__ wLo,
        const float* __restrict__ bl,
        float* __restrict__ outf,
        unsigned short* __restrict__ outb,
        int nNodes) {
    const int l = threadIdx.x & 63;
    const int wv = threadIdx.x >> 6;
    const int col = l & 15, grp = l >> 4;
    const int base0 = blockIdx.x * 256 + wv * 64;
    if (base0 >= nNodes) return;

    bf16x8v gH[4][2], sH[4][2];   // [tile][h]
    #pragma unroll
    for (int tt = 0; tt < 4; ++tt) {
        const int anode = min(base0 + tt * 16 + col, nNodes - 1);
        #pragma unroll
        for (int h = 0; h < 2; ++h) {
            gH[tt][h] = *(const bf16x8v*)(aggb + (size_t)anode * D + h * 32 + grp * 8);
            sH[tt][h] = *(const bf16x8v*)(xin  + (size_t)anode * D + h * 32 + grp * 8);
        }
    }

    f32x4v acc[4][4];
    #pragma unroll
    for (int tt = 0; tt < 4; ++tt)
        #pragma unroll
        for (int t = 0; t < 4; ++t) acc[tt][t] = (f32x4v){0.f, 0.f, 0.f, 0.f};

    #pragma unroll
    for (int t = 0; t < 4; ++t) {
        const unsigned short* whl = wHi + (size_t)(t * 16 + col) * D;
        const unsigned short* wol = wLo + (size_t)(t * 16 + col) * D;
        const unsigned short* whr = whl + 4096;
        const unsigned short* wor = wol + 4096;
        #pragma unroll
        for (int h = 0; h < 2; ++h) {
            const int k0 = h * 32 + grp * 8;
            bf16x8v bh  = *(const bf16x8v*)(whl + k0);
            bf16x8v bo  = *(const bf16x8v*)(wol + k0);
            bf16x8v bh2 = *(const bf16x8v*)(whr + k0);
            bf16x8v bo2 = *(const bf16x8v*)(wor + k0);
            #pragma unroll
            for (int tt = 0; tt < 4; ++tt) {
                acc[tt][t] = __builtin_amdgcn_mfma_f32_16x16x32_bf16(gH[tt][h], bh,  acc[tt][t], 0, 0, 0);
                acc[tt][t] = __builtin_amdgcn_mfma_f32_16x16x32_bf16(gH[tt][h], bo,  acc[tt][t], 0, 0, 0);
                acc[tt][t] = __builtin_amdgcn_mfma_f32_16x16x32_bf16(sH[tt][h], bh2, acc[tt][t], 0, 0, 0);
                acc[tt][t] = __builtin_amdgcn_mfma_f32_16x16x32_bf16(sH[tt][h], bo2, acc[tt][t], 0, 0, 0);
            }
        }
    }

    #pragma unroll
    for (int tt = 0; tt < 4; ++tt) {
        const int base = base0 + tt * 16;
        #pragma unroll
        for (int t = 0; t < 4; ++t) {
            float b = bl[t * 16 + col];
            #pragma unroll
            for (int r = 0; r < 4; ++r) acc[tt][t][r] += b;
        }
        if (LAYER == 0) {
            #pragma unroll
            for (int t = 0; t < 4; ++t)
                #pragma unroll
                for (int r = 0; r < 4; ++r) {
                    int n = base + grp * 4 + r;
                    if (n < nNodes)
                        outb[(size_t)n * D + t * 16 + col] = f2bf(fmaxf(acc[tt][t][r], 0.f));
                }
        } else {
            float ss[4] = {0.f, 0.f, 0.f, 0.f};
            #pragma unroll
            for (int t = 0; t < 4; ++t)
                #pragma unroll
                for (int r = 0; r < 4; ++r) ss[r] += acc[tt][t][r] * acc[tt][t][r];
            #pragma unroll
            for (int r = 0; r < 4; ++r) {
                #pragma unroll
                for (int off = 1; off < 16; off <<= 1) ss[r] += __shfl_xor(ss[r], off, 64);
            }
            float inv[4];
            #pragma unroll
            for (int r = 0; r < 4; ++r) inv[r] = 1.0f / fmaxf(sqrtf(ss[r]), 1e-12f);
            #pragma unroll
            for (int t = 0; t < 4; ++t)
                #pragma unroll
                for (int r = 0; r < 4; ++r) {
                    int n = base + grp * 4 + r;
                    if (n < nNodes)
                        outf[(size_t)n * D + t * 16 + col] = acc[tt][t][r] * inv[r];
                }
        }
    }
}

// ---------------- fallback: atomic scatter path (ws too small) -------------

__global__ void detect_idx64(const int* __restrict__ ei, int* __restrict__ flag) {
    int v = ei[2 * threadIdx.x + 1];
    unsigned long long b = __ballot(v != 0);
    if (threadIdx.x == 0) flag[0] = (b == 0ULL) ? 1 : 0;
}

__global__ __launch_bounds__(256) void sage_scatter(
        const float* __restrict__ x,
        const void* __restrict__ eidx,
        const int* __restrict__ flagp,
        float* __restrict__ agg,
        float* __restrict__ deg,
        int nE, int doDeg) {
    const bool idx64 = (*flagp != 0);
    const int lane = threadIdx.x & 63;
    int wave = (int)((blockIdx.x * blockDim.x + threadIdx.x) >> 6);
    const int waveStride = (int)((gridDim.x * blockDim.x) >> 6);
    const int* __restrict__ ei32 = (const int*)eidx;
    const long long* __restrict__ ei64 = (const long long*)eidx;
    for (int e = wave; e < nE; e += waveStride) {
        int s, d;
        if (idx64) { s = (int)ei64[e]; d = (int)ei64[e + nE]; }
        else       { s = ei32[e];      d = ei32[e + nE]; }
        atomicAdd(&agg[(size_t)d * D + lane], x[(size_t)s * D + lane]);
        if (doDeg && lane == 0) atomicAdd(&deg[d], 1.0f);
    }
}

__global__ __launch_bounds__(256) void sage_update(
        const float* __restrict__ xin,
        const float* __restrict__ agg,
        const float* __restrict__ deg,
        const float* __restrict__ wl,
        const float* __restrict__ bl,
        const float* __restrict__ wr,
        float* __restrict__ xout,
        int nNodes, int mode) {
    __shared__ float wlT[D * D];
    __shared__ float wrT[D * D];
    __shared__ float rowA[4][D];
    __shared__ float rowX[4][D];
    for (int i = threadIdx.x; i < D * D; i += blockDim.x) {
        int f = i >> 6, k = i & 63;
        wlT[k * D + f] = wl[i];
        wrT[k * D + f] = wr[i];
    }
    __syncthreads();
    const int lane = threadIdx.x & 63;
    const int wid = threadIdx.x >> 6;
    const float blv = bl[lane];
    for (int node = blockIdx.x * 4 + wid; node < nNodes; node += gridDim.x * 4) {
        float dg = fmaxf(deg[node], 1.0f);
        float a  = agg[(size_t)node * D + lane] / dg;
        float xv = xin[(size_t)node * D + lane];
        rowA[wid][lane] = a;
        rowX[wid][lane] = xv;
        float acc = blv;
        #pragma unroll
        for (int k = 0; k < D; ++k) {
            acc = fmaf(rowA[wid][k], wlT[k * D + lane], acc);
            acc = fmaf(rowX[wid][k], wrT[k * D + lane], acc);
        }
        if (mode == 0) {
            xout[(size_t)node * D + lane] = fmaxf(acc, 0.0f);
        } else {
            float ss = acc * acc;
            #pragma unroll
            for (int off = 32; off >= 1; off >>= 1) ss += __shfl_xor(ss, off, 64);
            xout[(size_t)node * D + lane] = acc / fmaxf(sqrtf(ss), 1e-12f);
        }
    }
}

extern "C" void kernel_launch(void* const* d_in, const int* in_sizes, int n_in,
                              void* d_out, int out_size, void* d_ws, size_t ws_size,
                              hipStream_t stream) {
    const float* x   = (const float*)d_in[0];
    const float* wl0 = (const float*)d_in[1];
    const float* bl0 = (const float*)d_in[2];
    const float* wr0 = (const float*)d_in[3];
    const float* wl1 = (const float*)d_in[4];
    const float* bl1 = (const float*)d_in[5];
    const float* wr1 = (const float*)d_in[6];
    const void*  ei  = d_in[7];
    float* out = (float*)d_out;

    const int N = in_sizes[0] / D;
    const int E = in_sizes[7] / 2;
    const int NB = (N + BN - 1) / BN;        // 391 for N=100000
    const int EPB = (E + NBLK - 1) / NBLK;
    const int TOTAL = NB << NBLK_LOG;
    const int NPARTS = (TOTAL + SCHUNK - 1) / SCHUNK;   // 25 for N=100000

    char* ws = (char*)d_ws;
    size_t off = 0;
    auto alloc = [&](size_t bytes) { void* p = ws + off; off = (off + bytes + 255) & ~(size_t)255; return p; };

    size_t need = 0;
    {
        size_t o = 0;
        auto sim = [&](size_t b) { o = (o + b + 255) & ~(size_t)255; };
        sim(4); sim(16384 * 2); sim(16384 * 2);
        sim(((size_t)MAXB << NBLK_LOG) * 4); sim(64 * 4); sim(((size_t)MAXB + 1) * 4);
        sim(((size_t)N + 1) * 4); sim((size_t)E * 4); sim((size_t)E * 4);
        sim((size_t)N * D * 2); sim((size_t)N * D * 2); sim((size_t)N * D * 2);
        need = o;
    }

    if (ws_size >= need && NB <= MAXB && NPARTS <= 64) {
        int* flag     = (int*)alloc(4);   // unused on fast path; kept for layout
        unsigned short* whi = (unsigned short*)alloc(16384 * 2);
        unsigned short* wlo = (unsigned short*)alloc(16384 * 2);
        int* H        = (int*)alloc(((size_t)MAXB << NBLK_LOG) * 4);
        int* part     = (int*)alloc(64 * 4);
        int* bbase    = (int*)alloc(((size_t)MAXB + 1) * 4);
        int* rowStart = (int*)alloc(((size_t)N + 1) * 4);
        int* srcs     = (int*)alloc((size_t)E * 4);
        unsigned* pairs = (unsigned*)alloc((size_t)E * 4);
        unsigned short* xb   = (unsigned short*)alloc((size_t)N * D * 2);
        unsigned short* x1b  = (unsigned short*)alloc((size_t)N * D * 2);
        unsigned short* aggb = (unsigned short*)alloc((size_t)N * D * 2);
        (void)flag;

        prep_hist<<<64 + NXBF + NBLK, 256, 0, stream>>>(
            wl0, wr0, wl1, wr1, whi, wlo,
            x, (uint4*)xb, N * 8,
            ei, H, E, NB, EPB);
        scan_h_partial<<<NPARTS, 256, 0, stream>>>(H, part, TOTAL);
        scan_h_final<<<NPARTS, 256, 0, stream>>>(H, part, bbase, TOTAL, NPARTS, NB, E);
        fill2<<<NBLK, 256, 0, stream>>>(ei, H, pairs, E, NB, EPB);
        bucket_to_csr<<<NB, 256, 0, stream>>>(pairs, bbase, rowStart, srcs, N, NB, E);

        const int gGather = (N + 31) / 32;
        const int gMfma   = (N + 255) / 256;
        // layer 0
        gather_mean_bf16<<<gGather, 256, 0, stream>>>(xb, rowStart, srcs, aggb, N);
        gemm_mfma<0><<<gMfma, 256, 0, stream>>>(aggb, xb, whi, wlo, bl0,
                                                (float*)0, x1b, N);
        // layer 1
        gather_mean_bf16<<<gGather, 256, 0, stream>>>(x1b, rowStart, srcs, aggb, N);
        gemm_mfma<1><<<gMfma, 256, 0, stream>>>(aggb, x1b, whi + 2 * 4096, wlo + 2 * 4096,
                                                bl1, out, (unsigned short*)0, N);
    } else {
        // fallback: round-1 scatter path (~26 MB ws)
        int*   flag = (int*)alloc(4);
        float* deg  = (float*)alloc((size_t)N * 4);
        float* agg  = (float*)alloc((size_t)N * D * 4);
        float* x1   = out;  // safe: sage_update reads only its own row of xin

        detect_idx64<<<1, 64, 0, stream>>>((const int*)ei, flag);
        hipMemsetAsync(deg, 0, ((size_t)N + (size_t)N * D) * 4, stream);
        sage_scatter<<<4096, 256, 0, stream>>>(x, ei, flag, agg, deg, E, 1);
        sage_update<<<2048, 256, 0, stream>>>(x, agg, deg, wl0, bl0, wr0, x1, N, 0);
        hipMemsetAsync(agg, 0, (size_t)N * D * 4, stream);
        sage_scatter<<<4096, 256, 0, stream>>>(x1, ei, flag, agg, deg, E, 0);
        sage_update<<<2048, 256, 0, stream>>>(x1, agg, deg, wl1, bl1, wr1, out, N, 1);
    }
}

// Round 15
// 153.016 us; speedup vs baseline: 1.4364x; 1.0031x over previous
//
#include <hip/hip_runtime.h>
#include <math.h>

#define D 64
#define BSHIFT 8      // bucket = dst >> 8 (256 nodes per bucket)
#define BN 256        // nodes per bucket
#define MAXB 512      // max buckets (N <= 131072 -> src fits 20 bits)
#define NBLK 256      // partition blocks for hist/fill2
#define NBLK_LOG 8
#define SCHUNK 4096   // H entries per scan block (256 thr x 16)
#define NXBF 1024     // conversion blocks inside prep_hist

typedef short bf16x8v __attribute__((ext_vector_type(8)));
typedef float f32x4v __attribute__((ext_vector_type(4)));

__device__ __forceinline__ unsigned short f2bf(float f) {   // round-to-nearest-even
    unsigned u = __float_as_uint(f);
    return (unsigned short)((u + 0x7FFFu + ((u >> 16) & 1u)) >> 16);
}
__device__ __forceinline__ float bf2f(unsigned short b) {
    return __uint_as_float(((unsigned)b) << 16);
}

// Per-wave inline int64-vs-int32 detection: all lanes read the same 64 odd
// words (L2-hot after the first block); ballot==0 -> int64 hi-halves.
__device__ __forceinline__ bool is_idx64(const int* __restrict__ ei32) {
    int v = ei32[2 * (threadIdx.x & 63) + 1];
    return __ballot(v != 0) == 0ULL;
}

// Fused prep: blocks [0,64) = weight hi/lo split; [64,64+NXBF) = x->bf16;
// [64+NXBF, 64+NXBF+NBLK) = edge histogram (H[bucket][blk]).
__global__ __launch_bounds__(256) void prep_hist(
        const float* __restrict__ w0, const float* __restrict__ w1,
        const float* __restrict__ w2, const float* __restrict__ w3,
        unsigned short* __restrict__ hi, unsigned short* __restrict__ lo,
        const float* __restrict__ x, uint4* __restrict__ xb4, int total8,
        const void* __restrict__ eidx, int* __restrict__ H,
        int nE, int nb, int epb) {
    const int b = blockIdx.x;
    if (b < 64) {
        int i = b * 256 + threadIdx.x;                 // 0..16383
        const float* ws_[4] = {w0, w1, w2, w3};
        float f = ws_[i >> 12][i & 4095];
        unsigned short h = f2bf(f);
        hi[i] = h;
        lo[i] = f2bf(f - bf2f(h));
        return;
    }
    if (b < 64 + NXBF) {
        int i = (b - 64) * 256 + threadIdx.x;
        int stride = NXBF * 256;
        for (; i < total8; i += stride) {
            float4 u0 = *(const float4*)(x + (size_t)i * 8);
            float4 u1 = *(const float4*)(x + (size_t)i * 8 + 4);
            uint4 p;
            p.x = (unsigned)f2bf(u0.x) | ((unsigned)f2bf(u0.y) << 16);
            p.y = (unsigned)f2bf(u0.z) | ((unsigned)f2bf(u0.w) << 16);
            p.z = (unsigned)f2bf(u1.x) | ((unsigned)f2bf(u1.y) << 16);
            p.w = (unsigned)f2bf(u1.z) | ((unsigned)f2bf(u1.w) << 16);
            xb4[i] = p;
        }
        return;
    }
    // ---- histogram part ----
    __shared__ int h[MAXB];
    const int hb = b - (64 + NXBF);
    const int* __restrict__ ei32 = (const int*)eidx;
    const long long* __restrict__ ei64 = (const long long*)eidx;
    const bool idx64 = is_idx64(ei32);
    for (int i = threadIdx.x; i < nb; i += 256) h[i] = 0;
    __syncthreads();
    const int e0 = hb * epb;
    const int e1 = min(e0 + epb, nE);
    if (!(nE & 1) && !(epb & 1)) {
        // vectorized: 2 edges per thread per iteration
        for (int e = e0 + threadIdx.x * 2; e < e1; e += 512) {
            int d0, d1 = -1;
            if (idx64) {
                if (e + 1 < e1) {
                    longlong2 dd = *(const longlong2*)(ei64 + nE + e);
                    d0 = (int)dd.x; d1 = (int)dd.y;
                } else d0 = (int)ei64[nE + e];
            } else {
                if (e + 1 < e1) {
                    int2 dd = *(const int2*)(ei32 + nE + e);
                    d0 = dd.x; d1 = dd.y;
                } else d0 = ei32[nE + e];
            }
            atomicAdd(&h[d0 >> BSHIFT], 1);
            if (d1 >= 0) atomicAdd(&h[d1 >> BSHIFT], 1);
        }
    } else {
        for (int e = e0 + threadIdx.x; e < e1; e += 256) {
            int d = idx64 ? (int)ei64[e + nE] : ei32[e + nE];
            atomicAdd(&h[d >> BSHIFT], 1);
        }
    }
    __syncthreads();
    for (int i = threadIdx.x; i < nb; i += 256)
        H[(i << NBLK_LOG) + hb] = h[i];
}

// ---------------- deterministic counting-sort CSR build ----------------

__global__ __launch_bounds__(256) void scan_h_partial(
        const int* __restrict__ H, int* __restrict__ part, int total) {
    __shared__ int red[4];
    int base = blockIdx.x * SCHUNK + threadIdx.x * 16;
    int s = 0;
    #pragma unroll
    for (int k = 0; k < 16; ++k) { int i = base + k; if (i < total) s += H[i]; }
    #pragma unroll
    for (int off = 32; off >= 1; off >>= 1) s += __shfl_xor(s, off, 64);
    int lane = threadIdx.x & 63, wid = threadIdx.x >> 6;
    if (lane == 0) red[wid] = s;
    __syncthreads();
    if (threadIdx.x == 0) part[blockIdx.x] = red[0] + red[1] + red[2] + red[3];
}

// Folds the mid-scan: each block wave-scans raw part[] (<=64 entries) and
// shuffles out its own exclusive offset. Writes exclusive positions back to
// H, bucket bases to bbase, and bbase[nb] = E.
__global__ __launch_bounds__(256) void scan_h_final(
        int* __restrict__ H, const int* __restrict__ part,
        int* __restrict__ bbase, int total, int nParts, int nb, int nE) {
    __shared__ int wtot[4];
    int tid = threadIdx.x, lane = tid & 63, wid = tid >> 6;
    int pv = (lane < nParts) ? part[lane] : 0;
    int px = pv;
    #pragma unroll
    for (int off = 1; off < 64; off <<= 1) { int y = __shfl_up(px, off, 64); if (lane >= off) px += y; }
    int blockOff = (blockIdx.x == 0) ? 0 : __shfl(px, blockIdx.x - 1, 64);

    int base = blockIdx.x * SCHUNK + tid * 16;
    int v[16]; int t = 0;
    #pragma unroll
    for (int k = 0; k < 16; ++k) { int i = base + k; v[k] = (i < total) ? H[i] : 0; t += v[k]; }
    int x = t;
    #pragma unroll
    for (int off = 1; off < 64; off <<= 1) { int y = __shfl_up(x, off, 64); if (lane >= off) x += y; }
    if (lane == 63) wtot[wid] = x;
    __syncthreads();
    int woff = 0;
    for (int w = 0; w < wid; ++w) woff += wtot[w];
    int run = blockOff + woff + (x - t);
    #pragma unroll
    for (int k = 0; k < 16; ++k) {
        int i = base + k;
        if (i < total) {
            H[i] = run;
            if ((i & (NBLK - 1)) == 0) bbase[i >> NBLK_LOG] = run;
            run += v[k];
        }
    }
    if (blockIdx.x == 0 && tid == 0) bbase[nb] = nE;
}

// Packed 4-B pairs: src (bits 0..19) | local-dst (bits 20..27).
__global__ __launch_bounds__(256) void fill2(
        const void* __restrict__ eidx,
        const int* __restrict__ H, unsigned* __restrict__ pairs,
        int nE, int nb, int epb) {
    __shared__ int cur[MAXB];
    const int* __restrict__ ei32 = (const int*)eidx;
    const long long* __restrict__ ei64 = (const long long*)eidx;
    const bool idx64 = is_idx64(ei32);
    for (int i = threadIdx.x; i < nb; i += 256)
        cur[i] = H[(i << NBLK_LOG) + blockIdx.x];
    __syncthreads();
    const int e0 = blockIdx.x * epb;
    const int e1 = min(e0 + epb, nE);
    if (!(nE & 1) && !(epb & 1)) {
        for (int e = e0 + threadIdx.x * 2; e < e1; e += 512) {
            int s0, d0, s1 = -1, d1 = 0;
            if (idx64) {
                if (e + 1 < e1) {
                    longlong2 ss = *(const longlong2*)(ei64 + e);
                    longlong2 dd = *(const longlong2*)(ei64 + nE + e);
                    s0 = (int)ss.x; s1 = (int)ss.y; d0 = (int)dd.x; d1 = (int)dd.y;
                } else { s0 = (int)ei64[e]; d0 = (int)ei64[nE + e]; }
            } else {
                if (e + 1 < e1) {
                    int2 ss = *(const int2*)(ei32 + e);
                    int2 dd = *(const int2*)(ei32 + nE + e);
                    s0 = ss.x; s1 = ss.y; d0 = dd.x; d1 = dd.y;
                } else { s0 = ei32[e]; d0 = ei32[nE + e]; }
            }
            int pos0 = atomicAdd(&cur[d0 >> BSHIFT], 1);
            pairs[pos0] = (unsigned)s0 | ((unsigned)(d0 & (BN - 1)) << 20);
            if (s1 >= 0) {
                int pos1 = atomicAdd(&cur[d1 >> BSHIFT], 1);
                pairs[pos1] = (unsigned)s1 | ((unsigned)(d1 & (BN - 1)) << 20);
            }
        }
    } else {
        for (int e = e0 + threadIdx.x; e < e1; e += 256) {
            int s, d;
            if (idx64) { s = (int)ei64[e]; d = (int)ei64[e + nE]; }
            else       { s = ei32[e];      d = ei32[e + nE]; }
            int pos = atomicAdd(&cur[d >> BSHIFT], 1);
            pairs[pos] = (unsigned)s | ((unsigned)(d & (BN - 1)) << 20);
        }
    }
}

// One block (256 thr) per bucket of 256 nodes.
__global__ __launch_bounds__(256) void bucket_to_csr(
        const unsigned* __restrict__ pairs,
        const int* __restrict__ bbase,
        int* __restrict__ rowStart, int* __restrict__ srcs,
        int N, int nb, int nE) {
    __shared__ int lcnt[BN];
    __shared__ int lcur[BN];
    __shared__ int wtot[4];
    const int b = blockIdx.x;
    const int base = bbase[b];
    const int cnt  = bbase[b + 1] - base;
    const int tid = threadIdx.x, lane = tid & 63, wid = tid >> 6;
    lcnt[tid] = 0;
    __syncthreads();
    for (int i = tid; i < cnt; i += 256)
        atomicAdd(&lcnt[(int)(pairs[base + i] >> 20)], 1);
    __syncthreads();
    int v = lcnt[tid];
    int x = v;
    #pragma unroll
    for (int off = 1; off < 64; off <<= 1) { int y = __shfl_up(x, off, 64); if (lane >= off) x += y; }
    if (lane == 63) wtot[wid] = x;
    __syncthreads();
    if (tid == 0) {
        int r = 0;
        for (int w = 0; w < 4; ++w) { int t = wtot[w]; wtot[w] = r; r += t; }
    }
    __syncthreads();
    int excl = wtot[wid] + (x - v);
    lcur[tid] = excl;
    int node = b * BN + tid;
    if (node < N) rowStart[node] = base + excl;
    if (b == nb - 1 && tid == 0) rowStart[N] = nE;
    __syncthreads();
    for (int i = tid; i < cnt; i += 256) {
        unsigned p = pairs[base + i];
        int pos = atomicAdd(&lcur[(int)(p >> 20)], 1);
        srcs[base + pos] = (int)(p & 0xFFFFFu);
    }
}

// ---------------- layer stage 1: gather + mean (bf16 in, bf16 out) ---------
// 8 lanes per node, 32 nodes/block. srcs shared via coalesced load + shfl
// (1 load + shuffles per 8 edges instead of 8 redundant loads per lane).
#define UNPK8(v, arr)                                                     \
    do {                                                                  \
        arr[0] += __uint_as_float((v).x << 16);                           \
        arr[1] += __uint_as_float((v).x & 0xFFFF0000u);                   \
        arr[2] += __uint_as_float((v).y << 16);                           \
        arr[3] += __uint_as_float((v).y & 0xFFFF0000u);                   \
        arr[4] += __uint_as_float((v).z << 16);                           \
        arr[5] += __uint_as_float((v).z & 0xFFFF0000u);                   \
        arr[6] += __uint_as_float((v).w << 16);                           \
        arr[7] += __uint_as_float((v).w & 0xFFFF0000u);                   \
    } while (0)

__global__ __launch_bounds__(256) void gather_mean_bf16(
        const unsigned short* __restrict__ xb,
        const int* __restrict__ rowStart,
        const int* __restrict__ srcs,
        unsigned short* __restrict__ aggb,
        int nNodes) {
    const int tid = threadIdx.x;
    const int gl = tid & 7;
    const int grp = tid >> 3;
    const int node = blockIdx.x * 32 + grp;
    if (node >= nNodes) return;
    const int r0 = rowStart[node], r1 = rowStart[node + 1];
    float a[8] = {0.f,0.f,0.f,0.f,0.f,0.f,0.f,0.f};
    const unsigned short* xp = xb + gl * 8;
    const int wbase = (tid & 63) & ~7;   // group base lane within wave
    int j = r0;
    for (; j + 8 <= r1; j += 8) {
        int mysrc = srcs[j + gl];        // coalesced: 8 lanes read 8 ints
        int s0 = __shfl(mysrc, wbase + 0, 64);
        int s1 = __shfl(mysrc, wbase + 1, 64);
        int s2 = __shfl(mysrc, wbase + 2, 64);
        int s3 = __shfl(mysrc, wbase + 3, 64);
        int s4 = __shfl(mysrc, wbase + 4, 64);
        int s5 = __shfl(mysrc, wbase + 5, 64);
        int s6 = __shfl(mysrc, wbase + 6, 64);
        int s7 = __shfl(mysrc, wbase + 7, 64);
        uint4 v0 = *(const uint4*)(xp + (size_t)s0 * D);
        uint4 v1 = *(const uint4*)(xp + (size_t)s1 * D);
        uint4 v2 = *(const uint4*)(xp + (size_t)s2 * D);
        uint4 v3 = *(const uint4*)(xp + (size_t)s3 * D);
        uint4 v4 = *(const uint4*)(xp + (size_t)s4 * D);
        uint4 v5 = *(const uint4*)(xp + (size_t)s5 * D);
        uint4 v6 = *(const uint4*)(xp + (size_t)s6 * D);
        uint4 v7 = *(const uint4*)(xp + (size_t)s7 * D);
        UNPK8(v0, a); UNPK8(v1, a); UNPK8(v2, a); UNPK8(v3, a);
        UNPK8(v4, a); UNPK8(v5, a); UNPK8(v6, a); UNPK8(v7, a);
    }
    if (j < r1) {
        const int rem = r1 - j;          // 1..7, uniform within group
        int mysrc = srcs[min(j + gl, r1 - 1)];
        #pragma unroll
        for (int k = 0; k < 7; ++k) {
            if (k < rem) {
                int sk = __shfl(mysrc, wbase + k, 64);
                uint4 v = *(const uint4*)(xp + (size_t)sk * D);
                UNPK8(v, a);
            }
        }
    }
    const float inv = 1.0f / fmaxf((float)(r1 - r0), 1.0f);
    uint4 p;
    p.x = (unsigned)f2bf(a[0]*inv) | ((unsigned)f2bf(a[1]*inv) << 16);
    p.y = (unsigned)f2bf(a[2]*inv) | ((unsigned)f2bf(a[3]*inv) << 16);
    p.z = (unsigned)f2bf(a[4]*inv) | ((unsigned)f2bf(a[5]*inv) << 16);
    p.w = (unsigned)f2bf(a[6]*inv) | ((unsigned)f2bf(a[7]*inv) << 16);
    *(uint4*)(aggb + (size_t)node * D + gl * 8) = p;
}

// ---------------- layer stage 2: bf16 MFMA GEMM, 4 tiles/wave --------------
template<int LAYER>
__global__ __launch_bounds__(256) void gemm_mfma(
        const unsigned short* __restrict__ aggb,
        const unsigned short* __restrict__ xin,
        const unsigned short* __restrict__ wHi,
        const unsigned short* __restrict__ wLo,
        const float* __restrict__ bl,
        float* __restrict__ outf,
        unsigned short* __restrict__ outb,
        int nNodes) {
    const int l = threadIdx.x & 63;
    const int wv = threadIdx.x >> 6;
    const int col = l & 15, grp = l >> 4;
    const int base0 = blockIdx.x * 256 + wv * 64;
    if (base0 >= nNodes) return;

    bf16x8v gH[4][2], sH[4][2];   // [tile][h]
    #pragma unroll
    for (int tt = 0; tt < 4; ++tt) {
        const int anode = min(base0 + tt * 16 + col, nNodes - 1);
        #pragma unroll
        for (int h = 0; h < 2; ++h) {
            gH[tt][h] = *(const bf16x8v*)(aggb + (size_t)anode * D + h * 32 + grp * 8);
            sH[tt][h] = *(const bf16x8v*)(xin  + (size_t)anode * D + h * 32 + grp * 8);
        }
    }

    f32x4v acc[4][4];
    #pragma unroll
    for (int tt = 0; tt < 4; ++tt)
        #pragma unroll
        for (int t = 0; t < 4; ++t) acc[tt][t] = (f32x4v){0.f, 0.f, 0.f, 0.f};

    #pragma unroll
    for (int t = 0; t < 4; ++t) {
        const unsigned short* whl = wHi + (size_t)(t * 16 + col) * D;
        const unsigned short* wol = wLo + (size_t)(t * 16 + col) * D;
        const unsigned short* whr = whl + 4096;
        const unsigned short* wor = wol + 4096;
        #pragma unroll
        for (int h = 0; h < 2; ++h) {
            const int k0 = h * 32 + grp * 8;
            bf16x8v bh  = *(const bf16x8v*)(whl + k0);
            bf16x8v bo  = *(const bf16x8v*)(wol + k0);
            bf16x8v bh2 = *(const bf16x8v*)(whr + k0);
            bf16x8v bo2 = *(const bf16x8v*)(wor + k0);
            #pragma unroll
            for (int tt = 0; tt < 4; ++tt) {
                acc[tt][t] = __builtin_amdgcn_mfma_f32_16x16x32_bf16(gH[tt][h], bh,  acc[tt][t], 0, 0, 0);
                acc[tt][t] = __builtin_amdgcn_mfma_f32_16x16x32_bf16(gH[tt][h], bo,  acc[tt][t], 0, 0, 0);
                acc[tt][t] = __builtin_amdgcn_mfma_f32_16x16x32_bf16(sH[tt][h], bh2, acc[tt][t], 0, 0, 0);
                acc[tt][t] = __builtin_amdgcn_mfma_f32_16x16x32_bf16(sH[tt][h], bo2, acc[tt][t], 0, 0, 0);
            }
        }
    }

    #pragma unroll
    for (int tt = 0; tt < 4; ++tt) {
        const int base = base0 + tt * 16;
        #pragma unroll
        for (int t = 0; t < 4; ++t) {
            float b = bl[t * 16 + col];
            #pragma unroll
            for (int r = 0; r < 4; ++r) acc[tt][t][r] += b;
        }
        if (LAYER == 0) {
            #pragma unroll
            for (int t = 0; t < 4; ++t)
                #pragma unroll
                for (int r = 0; r < 4; ++r) {
                    int n = base + grp * 4 + r;
                    if (n < nNodes)
                        outb[(size_t)n * D + t * 16 + col] = f2bf(fmaxf(acc[tt][t][r], 0.f));
                }
        } else {
            float ss[4] = {0.f, 0.f, 0.f, 0.f};
            #pragma unroll
            for (int t = 0; t < 4; ++t)
                #pragma unroll
                for (int r = 0; r < 4; ++r) ss[r] += acc[tt][t][r] * acc[tt][t][r];
            #pragma unroll
            for (int r = 0; r < 4; ++r) {
                #pragma unroll
                for (int off = 1; off < 16; off <<= 1) ss[r] += __shfl_xor(ss[r], off, 64);
            }
            float inv[4];
            #pragma unroll
            for (int r = 0; r < 4; ++r) inv[r] = 1.0f / fmaxf(sqrtf(ss[r]), 1e-12f);
            #pragma unroll
            for (int t = 0; t < 4; ++t)
                #pragma unroll
                for (int r = 0; r < 4; ++r) {
                    int n = base + grp * 4 + r;
                    if (n < nNodes)
                        outf[(size_t)n * D + t * 16 + col] = acc[tt][t][r] * inv[r];
                }
        }
    }
}

// ---------------- fallback: atomic scatter path (ws too small) -------------

__global__ void detect_idx64(const int* __restrict__ ei, int* __restrict__ flag) {
    int v = ei[2 * threadIdx.x + 1];
    unsigned long long b = __ballot(v != 0);
    if (threadIdx.x == 0) flag[0] = (b == 0ULL) ? 1 : 0;
}

__global__ __launch_bounds__(256) void sage_scatter(
        const float* __restrict__ x,
        const void* __restrict__ eidx,
        const int* __restrict__ flagp,
        float* __restrict__ agg,
        float* __restrict__ deg,
        int nE, int doDeg) {
    const bool idx64 = (*flagp != 0);
    const int lane = threadIdx.x & 63;
    int wave = (int)((blockIdx.x * blockDim.x + threadIdx.x) >> 6);
    const int waveStride = (int)((gridDim.x * blockDim.x) >> 6);
    const int* __restrict__ ei32 = (const int*)eidx;
    const long long* __restrict__ ei64 = (const long long*)eidx;
    for (int e = wave; e < nE; e += waveStride) {
        int s, d;
        if (idx64) { s = (int)ei64[e]; d = (int)ei64[e + nE]; }
        else       { s = ei32[e];      d = ei32[e + nE]; }
        atomicAdd(&agg[(size_t)d * D + lane], x[(size_t)s * D + lane]);
        if (doDeg && lane == 0) atomicAdd(&deg[d], 1.0f);
    }
}

__global__ __launch_bounds__(256) void sage_update(
        const float* __restrict__ xin,
        const float* __restrict__ agg,
        const float* __restrict__ deg,
        const float* __restrict__ wl,
        const float* __restrict__ bl,
        const float* __restrict__ wr,
        float* __restrict__ xout,
        int nNodes, int mode) {
    __shared__ float wlT[D * D];
    __shared__ float wrT[D * D];
    __shared__ float rowA[4][D];
    __shared__ float rowX[4][D];
    for (int i = threadIdx.x; i < D * D; i += blockDim.x) {
        int f = i >> 6, k = i & 63;
        wlT[k * D + f] = wl[i];
        wrT[k * D + f] = wr[i];
    }
    __syncthreads();
    const int lane = threadIdx.x & 63;
    const int wid = threadIdx.x >> 6;
    const float blv = bl[lane];
    for (int node = blockIdx.x * 4 + wid; node < nNodes; node += gridDim.x * 4) {
        float dg = fmaxf(deg[node], 1.0f);
        float a  = agg[(size_t)node * D + lane] / dg;
        float xv = xin[(size_t)node * D + lane];
        rowA[wid][lane] = a;
        rowX[wid][lane] = xv;
        float acc = blv;
        #pragma unroll
        for (int k = 0; k < D; ++k) {
            acc = fmaf(rowA[wid][k], wlT[k * D + lane], acc);
            acc = fmaf(rowX[wid][k], wrT[k * D + lane], acc);
        }
        if (mode == 0) {
            xout[(size_t)node * D + lane] = fmaxf(acc, 0.0f);
        } else {
            float ss = acc * acc;
            #pragma unroll
            for (int off = 32; off >= 1; off >>= 1) ss += __shfl_xor(ss, off, 64);
            xout[(size_t)node * D + lane] = acc / fmaxf(sqrtf(ss), 1e-12f);
        }
    }
}

extern "C" void kernel_launch(void* const* d_in, const int* in_sizes, int n_in,
                              void* d_out, int out_size, void* d_ws, size_t ws_size,
                              hipStream_t stream) {
    const float* x   = (const float*)d_in[0];
    const float* wl0 = (const float*)d_in[1];
    const float* bl0 = (const float*)d_in[2];
    const float* wr0 = (const float*)d_in[3];
    const float* wl1 = (const float*)d_in[4];
    const float* bl1 = (const float*)d_in[5];
    const float* wr1 = (const float*)d_in[6];
    const void*  ei  = d_in[7];
    float* out = (float*)d_out;

    const int N = in_sizes[0] / D;
    const int E = in_sizes[7] / 2;
    const int NB = (N + BN - 1) / BN;        // 391 for N=100000
    const int EPB = (E + NBLK - 1) / NBLK;
    const int TOTAL = NB << NBLK_LOG;
    const int NPARTS = (TOTAL + SCHUNK - 1) / SCHUNK;   // 25 for N=100000

    char* ws = (char*)d_ws;
    size_t off = 0;
    auto alloc = [&](size_t bytes) { void* p = ws + off; off = (off + bytes + 255) & ~(size_t)255; return p; };

    size_t need = 0;
    {
        size_t o = 0;
        auto sim = [&](size_t b) { o = (o + b + 255) & ~(size_t)255; };
        sim(4); sim(16384 * 2); sim(16384 * 2);
        sim(((size_t)MAXB << NBLK_LOG) * 4); sim(64 * 4); sim(((size_t)MAXB + 1) * 4);
        sim(((size_t)N + 1) * 4); sim((size_t)E * 4); sim((size_t)E * 4);
        sim((size_t)N * D * 2); sim((size_t)N * D * 2); sim((size_t)N * D * 2);
        need = o;
    }

    if (ws_size >= need && NB <= MAXB && NPARTS <= 64) {
        int* flag     = (int*)alloc(4);   // unused on fast path; kept for layout
        unsigned short* whi = (unsigned short*)alloc(16384 * 2);
        unsigned short* wlo = (unsigned short*)alloc(16384 * 2);
        int* H        = (int*)alloc(((size_t)MAXB << NBLK_LOG) * 4);
        int* part     = (int*)alloc(64 * 4);
        int* bbase    = (int*)alloc(((size_t)MAXB + 1) * 4);
        int* rowStart = (int*)alloc(((size_t)N + 1) * 4);
        int* srcs     = (int*)alloc((size_t)E * 4);
        unsigned* pairs = (unsigned*)alloc((size_t)E * 4);
        unsigned short* xb   = (unsigned short*)alloc((size_t)N * D * 2);
        unsigned short* x1b  = (unsigned short*)alloc((size_t)N * D * 2);
        unsigned short* aggb = (unsigned short*)alloc((size_t)N * D * 2);
        (void)flag;

        prep_hist<<<64 + NXBF + NBLK, 256, 0, stream>>>(
            wl0, wr0, wl1, wr1, whi, wlo,
            x, (uint4*)xb, N * 8,
            ei, H, E, NB, EPB);
        scan_h_partial<<<NPARTS, 256, 0, stream>>>(H, part, TOTAL);
        scan_h_final<<<NPARTS, 256, 0, stream>>>(H, part, bbase, TOTAL, NPARTS, NB, E);
        fill2<<<NBLK, 256, 0, stream>>>(ei, H, pairs, E, NB, EPB);
        bucket_to_csr<<<NB, 256, 0, stream>>>(pairs, bbase, rowStart, srcs, N, NB, E);

        const int gGather = (N + 31) / 32;
        const int gMfma   = (N + 255) / 256;
        // layer 0
        gather_mean_bf16<<<gGather, 256, 0, stream>>>(xb, rowStart, srcs, aggb, N);
        gemm_mfma<0><<<gMfma, 256, 0, stream>>>(aggb, xb, whi, wlo, bl0,
                                                (float*)0, x1b, N);
        // layer 1
        gather_mean_bf16<<<gGather, 256, 0, stream>>>(x1b, rowStart, srcs, aggb, N);
        gemm_mfma<1><<<gMfma, 256, 0, stream>>>(aggb, x1b, whi + 2 * 4096, wlo + 2 * 4096,
                                                bl1, out, (unsigned short*)0, N);
    } else {
        // fallback: round-1 scatter path (~26 MB ws)
        int*   flag = (int*)alloc(4);
        float* deg  = (float*)alloc((size_t)N * 4);
        float* agg  = (float*)alloc((size_t)N * D * 4);
        float* x1   = out;  // safe: sage_update reads only its own row of xin

        detect_idx64<<<1, 64, 0, stream>>>((const int*)ei, flag);
        hipMemsetAsync(deg, 0, ((size_t)N + (size_t)N * D) * 4, stream);
        sage_scatter<<<4096, 256, 0, stream>>>(x, ei, flag, agg, deg, E, 1);
        sage_update<<<2048, 256, 0, stream>>>(x, agg, deg, wl0, bl0, wr0, x1, N, 0);
        hipMemsetAsync(agg, 0, (size_t)N * D * 4, stream);
        sage_scatter<<<4096, 256, 0, stream>>>(x1, ei, flag, agg, deg, E, 0);
        sage_update<<<2048, 256, 0, stream>>>(x1, agg, deg, wl1, bl1, wr1, out, N, 1);
    }
}